// Round 1
// baseline (701.376 us; speedup 1.0000x reference)
//
#include <hip/hip_runtime.h>
#include <stdint.h>

typedef __attribute__((ext_vector_type(8))) __bf16 bf16x8;
typedef __attribute__((ext_vector_type(4))) float f32x4;
typedef __attribute__((ext_vector_type(8))) unsigned short u16x8;

#define SEQ 2048
#define HID 4608
#define NQKV 5632   // 4608 q + 512 k + 512 v
#define NHEAD 36
#define NKVH 4
#define HDIM 128
#define WINDOW 1024

__device__ __forceinline__ unsigned short f2b(float f) {
    unsigned u = __builtin_bit_cast(unsigned, f);
    u += 0x7fffu + ((u >> 16) & 1u);
    return (unsigned short)(u >> 16);
}
__device__ __forceinline__ float b2f(unsigned short h) {
    unsigned u = ((unsigned)h) << 16;
    return __builtin_bit_cast(float, u);
}

#define GLD16(gp, lp) __builtin_amdgcn_global_load_lds( \
    (const __attribute__((address_space(1))) void*)(gp), \
    (__attribute__((address_space(3))) void*)(lp), 16, 0, 0)

// ---------------- f32 -> bf16 convert ----------------
__global__ __launch_bounds__(256) void conv_kernel(const float* __restrict__ src,
                                                   unsigned short* __restrict__ dst, int n4) {
    int stride = gridDim.x * blockDim.x;
    for (int i = blockIdx.x * blockDim.x + threadIdx.x; i < n4; i += stride) {
        float4 v = ((const float4*)src)[i];
        ushort4 o;
        o.x = f2b(v.x); o.y = f2b(v.y); o.z = f2b(v.z); o.w = f2b(v.w);
        ((ushort4*)dst)[i] = o;
    }
}

// ---------------- GEMM: C[M,N] = A[M,K] @ W[N,K]^T + bias ----------------
// 128x128 tile, BK=32, 256 threads (4 waves, 2x2), mfma 16x16x32 bf16.
__global__ __launch_bounds__(256) void gemm_kernel(
    const unsigned short* __restrict__ A,
    const unsigned short* __restrict__ W,
    void* __restrict__ out,
    const float* __restrict__ b0, const float* __restrict__ b1, const float* __restrict__ b2,
    int N, int K, int outf32)
{
    __shared__ alignas(16) unsigned short As[128 * 32];
    __shared__ alignas(16) unsigned short Bs[128 * 32];
    const int tid = threadIdx.x;
    const int wid = tid >> 6, lane = tid & 63;
    const int r16 = lane & 15, kg = lane >> 4;
    const int row0 = blockIdx.y * 128, col0 = blockIdx.x * 128;
    const int wr = (wid >> 1) * 64, wc = (wid & 1) * 64;

    f32x4 acc[4][4] = {};

    const unsigned short* aSrc = A + (size_t)(row0 + wid * 16 + (lane >> 2)) * K + (lane & 3) * 8;
    const unsigned short* bSrc = W + (size_t)(col0 + wid * 16 + (lane >> 2)) * K + (lane & 3) * 8;
    char* asDst = (char*)As + wid * 1024;
    char* bsDst = (char*)Bs + wid * 1024;
    const size_t jump = (size_t)64 * K;

    for (int k0 = 0; k0 < K; k0 += 32) {
        GLD16(aSrc + k0,        asDst);
        GLD16(aSrc + k0 + jump, asDst + 4096);
        GLD16(bSrc + k0,        bsDst);
        GLD16(bSrc + k0 + jump, bsDst + 4096);
        __syncthreads();
        bf16x8 af[4], bfr[4];
#pragma unroll
        for (int m = 0; m < 4; ++m)
            af[m] = *(const bf16x8*)((const char*)As + (wr + m * 16 + r16) * 64 + kg * 16);
#pragma unroll
        for (int n = 0; n < 4; ++n)
            bfr[n] = *(const bf16x8*)((const char*)Bs + (wc + n * 16 + r16) * 64 + kg * 16);
#pragma unroll
        for (int m = 0; m < 4; ++m)
#pragma unroll
            for (int n = 0; n < 4; ++n)
                acc[m][n] = __builtin_amdgcn_mfma_f32_16x16x32_bf16(af[m], bfr[n], acc[m][n], 0, 0, 0);
        __syncthreads();
    }

    if (!outf32) {
        unsigned short* O = (unsigned short*)out;
#pragma unroll
        for (int m = 0; m < 4; ++m)
#pragma unroll
            for (int n = 0; n < 4; ++n)
#pragma unroll
                for (int r = 0; r < 4; ++r) {
                    int row = row0 + wr + m * 16 + kg * 4 + r;
                    int col = col0 + wc + n * 16 + r16;
                    float bias = (col < HID) ? b0[col]
                               : (col < HID + 512 ? b1[col - HID] : b2[col - HID - 512]);
                    O[(size_t)row * N + col] = f2b(acc[m][n][r] + bias);
                }
    } else {
        float* O = (float*)out;
#pragma unroll
        for (int m = 0; m < 4; ++m)
#pragma unroll
            for (int n = 0; n < 4; ++n)
#pragma unroll
                for (int r = 0; r < 4; ++r) {
                    int row = row0 + wr + m * 16 + kg * 4 + r;
                    int col = col0 + wc + n * 16 + r16;
                    O[(size_t)row * N + col] = acc[m][n][r] + b0[col];
                }
    }
}

// ---------------- RoPE in-place on q (heads 0..35) and k (36..39) ----------------
__global__ __launch_bounds__(256) void rope_kernel(unsigned short* __restrict__ qkv,
                                                   const float* __restrict__ cos_t,
                                                   const float* __restrict__ sin_t) {
    int idx = blockIdx.x * 256 + threadIdx.x;   // SEQ*40*64 threads
    int d = idx & 63;
    int t = idx >> 6;
    int head = t % 40;
    int s = t / 40;
    int base = head < NHEAD ? head * HDIM : HID + (head - NHEAD) * HDIM;
    size_t off = (size_t)s * NQKV + base;
    float x = b2f(qkv[off + d]);
    float y = b2f(qkv[off + d + 64]);
    float c = cos_t[s * HDIM + d];
    float sn = sin_t[s * HDIM + d];
    qkv[off + d]      = f2b(x * c - y * sn);
    qkv[off + d + 64] = f2b(y * c + x * sn);
}

// ---------------- flash attention, GQA + causal + sliding window ----------------
// grid (36 heads, 32 q-tiles of 64). 256 threads = 4 waves; wave owns 16 q rows.
#define KSTR 136   // Ks row stride (ushorts), padded
#define VSTR 88    // Vt row stride
#define PSTR 88    // P row stride
__global__ __launch_bounds__(256) void attn_kernel(const unsigned short* __restrict__ qkv,
                                                   unsigned short* __restrict__ aout)
{
    __shared__ alignas(16) unsigned short Ks[64 * KSTR];
    __shared__ alignas(16) unsigned short Vt[128 * VSTR];
    __shared__ alignas(16) unsigned short Ps[4 * 16 * PSTR];
    const int h = blockIdx.x, qb = blockIdx.y;
    const int q0 = qb * 64;
    const int kvh = h / 9;
    const int tid = threadIdx.x, wid = tid >> 6, lane = tid & 63;
    const int r16 = lane & 15, kg = lane >> 4;
    const int qbase = q0 + wid * 16;

    bf16x8 qf[4];
    {
        const unsigned short* qrow = qkv + (size_t)(qbase + r16) * NQKV + h * HDIM;
#pragma unroll
        for (int kk = 0; kk < 4; ++kk)
            qf[kk] = *(const bf16x8*)(qrow + kk * 32 + kg * 8);
    }

    f32x4 o[8] = {};
    float mrow[4], lrow[4];
#pragma unroll
    for (int r = 0; r < 4; ++r) { mrow[r] = -1e30f; lrow[r] = 0.f; }

    int lo = q0 - (WINDOW - 1); if (lo < 0) lo = 0; lo &= ~63;
    unsigned short* myP = Ps + wid * 16 * PSTR;
    const float scale = 0.08838834764831845f;  // 1/sqrt(128)

    for (int kt = lo; kt <= q0; kt += 64) {
        // stage K[64][128] and V^T[128][64]
        for (int c = tid; c < 1024; c += 256) {
            int key = c >> 4, dc = c & 15;
            const unsigned short* kp = qkv + (size_t)(kt + key) * NQKV + HID + kvh * HDIM + dc * 8;
            *(u16x8*)(Ks + key * KSTR + dc * 8) = *(const u16x8*)kp;
            const unsigned short* vp = qkv + (size_t)(kt + key) * NQKV + HID + 512 + kvh * HDIM + dc * 8;
            u16x8 vv = *(const u16x8*)vp;
#pragma unroll
            for (int j = 0; j < 8; ++j)
                Vt[(dc * 8 + j) * VSTR + key] = vv[j];
        }
        __syncthreads();

        // QK^T : sc[t] is 16q x 16k tile, keys kt + t*16 + r16
        f32x4 sc[4] = {};
#pragma unroll
        for (int t = 0; t < 4; ++t)
#pragma unroll
            for (int kk = 0; kk < 4; ++kk) {
                bf16x8 kf = *(const bf16x8*)(Ks + (t * 16 + r16) * KSTR + kk * 32 + kg * 8);
                sc[t] = __builtin_amdgcn_mfma_f32_16x16x32_bf16(qf[kk], kf, sc[t], 0, 0, 0);
            }

        // mask + online softmax (rows live in lane-group kg, reg r)
        float p[4][4], mt[4];
#pragma unroll
        for (int r = 0; r < 4; ++r) mt[r] = -1e30f;
#pragma unroll
        for (int t = 0; t < 4; ++t)
#pragma unroll
            for (int r = 0; r < 4; ++r) {
                int q = qbase + kg * 4 + r;
                int key = kt + t * 16 + r16;
                bool valid = (key <= q) && (q - key < WINDOW);
                float v = valid ? sc[t][r] * scale : -1e30f;
                p[t][r] = v;
                mt[r] = fmaxf(mt[r], v);
            }
#pragma unroll
        for (int mask = 1; mask <= 8; mask <<= 1)
#pragma unroll
            for (int r = 0; r < 4; ++r)
                mt[r] = fmaxf(mt[r], __shfl_xor(mt[r], mask, 64));

        float alpha[4], tsum[4];
#pragma unroll
        for (int r = 0; r < 4; ++r) {
            float mnew = fmaxf(mrow[r], mt[r]);
            alpha[r] = __expf(mrow[r] - mnew);
            mrow[r] = mnew;
            tsum[r] = 0.f;
        }
#pragma unroll
        for (int t = 0; t < 4; ++t)
#pragma unroll
            for (int r = 0; r < 4; ++r) {
                float e = __expf(p[t][r] - mrow[r]);
                p[t][r] = e;
                tsum[r] += e;
            }
#pragma unroll
        for (int mask = 1; mask <= 8; mask <<= 1)
#pragma unroll
            for (int r = 0; r < 4; ++r)
                tsum[r] += __shfl_xor(tsum[r], mask, 64);
#pragma unroll
        for (int r = 0; r < 4; ++r)
            lrow[r] = lrow[r] * alpha[r] + tsum[r];
#pragma unroll
        for (int n = 0; n < 8; ++n)
#pragma unroll
            for (int r = 0; r < 4; ++r)
                o[n][r] = o[n][r] * alpha[r];

        // write P (wave-private) then PV
#pragma unroll
        for (int t = 0; t < 4; ++t)
#pragma unroll
            for (int r = 0; r < 4; ++r)
                myP[(kg * 4 + r) * PSTR + t * 16 + r16] = f2b(p[t][r]);
        asm volatile("s_waitcnt lgkmcnt(0)" ::: "memory");

#pragma unroll
        for (int kc = 0; kc < 2; ++kc) {
            bf16x8 pa = *(const bf16x8*)(myP + r16 * PSTR + kc * 32 + kg * 8);
#pragma unroll
            for (int n = 0; n < 8; ++n) {
                bf16x8 vb = *(const bf16x8*)(Vt + (n * 16 + r16) * VSTR + kc * 32 + kg * 8);
                o[n] = __builtin_amdgcn_mfma_f32_16x16x32_bf16(pa, vb, o[n], 0, 0, 0);
            }
        }
        __syncthreads();
    }

#pragma unroll
    for (int n = 0; n < 8; ++n)
#pragma unroll
        for (int r = 0; r < 4; ++r) {
            int q = qbase + kg * 4 + r;
            aout[(size_t)q * HID + h * HDIM + n * 16 + r16] = f2b(o[n][r] / lrow[r]);
        }
}

extern "C" void kernel_launch(void* const* d_in, const int* in_sizes, int n_in,
                              void* d_out, int out_size, void* d_ws, size_t ws_size,
                              hipStream_t stream) {
    const float* hidden = (const float*)d_in[0];
    // d_in[1] position_ids == arange(S); used implicitly
    const float* cos_t = (const float*)d_in[2];
    const float* sin_t = (const float*)d_in[3];
    const float* q_w = (const float*)d_in[4];
    const float* q_b = (const float*)d_in[5];
    const float* k_w = (const float*)d_in[6];
    const float* k_b = (const float*)d_in[7];
    const float* v_w = (const float*)d_in[8];
    const float* v_b = (const float*)d_in[9];
    const float* o_w = (const float*)d_in[10];
    const float* o_b = (const float*)d_in[11];
    // d_in[12] sliding_window == 1024 (hardcoded)

    char* ws = (char*)d_ws;
    unsigned short* hbf  = (unsigned short*)ws;                   // 2048*4608 bf16
    unsigned short* attn = hbf;                                   // alias: reused after QKV GEMM
    unsigned short* wqkv = (unsigned short*)(ws + 18874368);      // 5632*4608 bf16 (q||k||v rows)
    unsigned short* wo   = (unsigned short*)(ws + 70778880);      // 4608*4608 bf16
    unsigned short* qkv  = (unsigned short*)(ws + 113246208);     // 2048*5632 bf16

    dim3 blk(256);
    conv_kernel<<<2048, blk, 0, stream>>>(hidden, hbf, (SEQ * HID) / 4);
    conv_kernel<<<2048, blk, 0, stream>>>(q_w, wqkv, (HID * HID) / 4);
    conv_kernel<<<2048, blk, 0, stream>>>(k_w, wqkv + (size_t)HID * HID, (512 * HID) / 4);
    conv_kernel<<<2048, blk, 0, stream>>>(v_w, wqkv + (size_t)5120 * HID, (512 * HID) / 4);
    conv_kernel<<<2048, blk, 0, stream>>>(o_w, wo, (HID * HID) / 4);

    gemm_kernel<<<dim3(44, 16), blk, 0, stream>>>(hbf, wqkv, qkv, q_b, k_b, v_b, NQKV, HID, 0);
    rope_kernel<<<(SEQ * 40 * 64) / 256, blk, 0, stream>>>(qkv, cos_t, sin_t);
    attn_kernel<<<dim3(NHEAD, SEQ / 64), blk, 0, stream>>>(qkv, attn);
    gemm_kernel<<<dim3(36, 16), blk, 0, stream>>>(attn, wo, d_out, o_b, nullptr, nullptr, HID, HID, 1);
}

// Round 2
// 535.003 us; speedup vs baseline: 1.3110x; 1.3110x over previous
//
#include <hip/hip_runtime.h>
#include <stdint.h>

typedef __attribute__((ext_vector_type(8))) __bf16 bf16x8;
typedef __attribute__((ext_vector_type(4))) float f32x4;
typedef __attribute__((ext_vector_type(8))) unsigned short u16x8;

#define SEQ 2048
#define HID 4608
#define NQKV 5632   // 4608 q + 512 k + 512 v
#define NHEAD 36
#define NKVH 4
#define HDIM 128
#define WINDOW 1024

__device__ __forceinline__ unsigned short f2b(float f) {
    unsigned u = __builtin_bit_cast(unsigned, f);
    u += 0x7fffu + ((u >> 16) & 1u);
    return (unsigned short)(u >> 16);
}
__device__ __forceinline__ float b2f(unsigned short h) {
    unsigned u = ((unsigned)h) << 16;
    return __builtin_bit_cast(float, u);
}

#define GLD16(gp, lp) __builtin_amdgcn_global_load_lds( \
    (const __attribute__((address_space(1))) void*)(gp), \
    (__attribute__((address_space(3))) void*)(lp), 16, 0, 0)

#define VMCNT8() asm volatile("s_waitcnt vmcnt(8)" ::: "memory")
#define VMCNT0() asm volatile("s_waitcnt vmcnt(0)" ::: "memory")

// ---------------- f32 -> bf16 convert ----------------
__global__ __launch_bounds__(256) void conv_kernel(const float* __restrict__ src,
                                                   unsigned short* __restrict__ dst, int n4) {
    int stride = gridDim.x * blockDim.x;
    for (int i = blockIdx.x * blockDim.x + threadIdx.x; i < n4; i += stride) {
        float4 v = ((const float4*)src)[i];
        ushort4 o;
        o.x = f2b(v.x); o.y = f2b(v.y); o.z = f2b(v.z); o.w = f2b(v.w);
        ((ushort4*)dst)[i] = o;
    }
}

// ---------------- GEMM 256x256 tile, BK=64, 8 waves, phase-split ----------------
// C[M,N] = A[M,K] @ W[N,K]^T + bias.  Counted-vmcnt pipeline + LDS chunk-XOR swizzle.
__global__ __launch_bounds__(512, 2) void gemm256_kernel(
    const unsigned short* __restrict__ A,
    const unsigned short* __restrict__ W,
    void* __restrict__ out,
    const float* __restrict__ b0, const float* __restrict__ b1, const float* __restrict__ b2,
    int N, int K, int GX, int outf32)
{
    // [buf][A=0/B=1][256 rows][64 k] bf16, chunk-swizzled: 128 KiB total
    __shared__ alignas(16) unsigned short lds[2][2][256 * 64];

    const int tid = threadIdx.x;
    const int w = tid >> 6, lane = tid & 63;
    const int r16 = lane & 15, kg = lane >> 4;
    const int wm = w >> 2, wn = w & 3;          // 2M x 4N waves

    // T1: bijective XCD swizzle (grid sizes here are multiples of 8)
    const int cpx = gridDim.x >> 3;
    const int o = blockIdx.x;
    const int id = (o & 7) * cpx + (o >> 3);
    const int bx = id % GX, by = id / GX;
    const int row0 = by * 256, col0 = bx * 256;

    // staging: lane covers 8-row group; pre-swizzled global chunk (rule #21)
    const int lr = lane >> 3;          // row within 8-row group
    const int lc = lane & 7;           // physical 16B chunk slot in LDS
    const int cg = lc ^ lr;            // logical chunk read from global
    const unsigned short* aP[4];
    const unsigned short* bP[4];
#pragma unroll
    for (int j = 0; j < 4; ++j) {
        const int L = w * 4 + j;       // 0..31, 8 rows each
        aP[j] = A + (size_t)(row0 + L * 8 + lr) * K + cg * 8;
        bP[j] = W + (size_t)(col0 + L * 8 + lr) * K + cg * 8;
    }

    const int NT = K >> 6;             // 64-wide K-tiles
    f32x4 acc[8][4] = {};

    // prologue: stage tile 0 into buf 0
#pragma unroll
    for (int j = 0; j < 4; ++j) GLD16(aP[j], (char*)&lds[0][0][0] + (w * 4 + j) * 1024);
#pragma unroll
    for (int j = 0; j < 4; ++j) GLD16(bP[j], (char*)&lds[0][1][0] + (w * 4 + j) * 1024);
#pragma unroll
    for (int j = 0; j < 4; ++j) { aP[j] += 64; bP[j] += 64; }

    const int swz = r16 & 7;
    for (int t = 0; t < NT; ++t) {
        const int cur = t & 1;
        if (t + 1 < NT) {
            const int nxt = cur ^ 1;
#pragma unroll
            for (int j = 0; j < 4; ++j) GLD16(aP[j], (char*)&lds[nxt][0][0] + (w * 4 + j) * 1024);
#pragma unroll
            for (int j = 0; j < 4; ++j) GLD16(bP[j], (char*)&lds[nxt][1][0] + (w * 4 + j) * 1024);
#pragma unroll
            for (int j = 0; j < 4; ++j) { aP[j] += 64; bP[j] += 64; }
            VMCNT8();                  // tile t landed; tile t+1 stays in flight
        } else {
            VMCNT0();
        }
        __builtin_amdgcn_s_barrier();

        const unsigned short* As_ = &lds[cur][0][0];
        const unsigned short* Bs_ = &lds[cur][1][0];

        bf16x8 af[4][2], bf0[2][2], bf1[2][2];
        // B frags: both n-halves of this wave's 64-col strip
#pragma unroll
        for (int ni = 0; ni < 2; ++ni)
#pragma unroll
            for (int kh = 0; kh < 2; ++kh) {
                int rb0 = wn * 64 + ni * 16 + r16;
                int rb1 = wn * 64 + 32 + ni * 16 + r16;
                bf0[ni][kh] = *(const bf16x8*)(Bs_ + rb0 * 64 + ((kh * 4 + kg) ^ swz) * 8);
                bf1[ni][kh] = *(const bf16x8*)(Bs_ + rb1 * 64 + ((kh * 4 + kg) ^ swz) * 8);
            }
        // A frags: m-half 0
#pragma unroll
        for (int mi = 0; mi < 4; ++mi)
#pragma unroll
            for (int kh = 0; kh < 2; ++kh) {
                int ra = wm * 128 + mi * 16 + r16;
                af[mi][kh] = *(const bf16x8*)(As_ + ra * 64 + ((kh * 4 + kg) ^ swz) * 8);
            }

        // phase 1: quadrant (0,0)
        __builtin_amdgcn_s_setprio(1);
#pragma unroll
        for (int mi = 0; mi < 4; ++mi)
#pragma unroll
            for (int ni = 0; ni < 2; ++ni)
#pragma unroll
                for (int kh = 0; kh < 2; ++kh)
                    acc[mi][ni] = __builtin_amdgcn_mfma_f32_16x16x32_bf16(af[mi][kh], bf0[ni][kh], acc[mi][ni], 0, 0, 0);
        __builtin_amdgcn_s_setprio(0);
        // phase 2: quadrant (0,1)
        __builtin_amdgcn_s_setprio(1);
#pragma unroll
        for (int mi = 0; mi < 4; ++mi)
#pragma unroll
            for (int ni = 0; ni < 2; ++ni)
#pragma unroll
                for (int kh = 0; kh < 2; ++kh)
                    acc[mi][2 + ni] = __builtin_amdgcn_mfma_f32_16x16x32_bf16(af[mi][kh], bf1[ni][kh], acc[mi][2 + ni], 0, 0, 0);
        __builtin_amdgcn_s_setprio(0);
        // A frags: m-half 1
#pragma unroll
        for (int mi = 0; mi < 4; ++mi)
#pragma unroll
            for (int kh = 0; kh < 2; ++kh) {
                int ra = wm * 128 + 64 + mi * 16 + r16;
                af[mi][kh] = *(const bf16x8*)(As_ + ra * 64 + ((kh * 4 + kg) ^ swz) * 8);
            }
        // phase 3: quadrant (1,1)
        __builtin_amdgcn_s_setprio(1);
#pragma unroll
        for (int mi = 0; mi < 4; ++mi)
#pragma unroll
            for (int ni = 0; ni < 2; ++ni)
#pragma unroll
                for (int kh = 0; kh < 2; ++kh)
                    acc[4 + mi][2 + ni] = __builtin_amdgcn_mfma_f32_16x16x32_bf16(af[mi][kh], bf1[ni][kh], acc[4 + mi][2 + ni], 0, 0, 0);
        __builtin_amdgcn_s_setprio(0);
        // phase 4: quadrant (1,0)
        __builtin_amdgcn_s_setprio(1);
#pragma unroll
        for (int mi = 0; mi < 4; ++mi)
#pragma unroll
            for (int ni = 0; ni < 2; ++ni)
#pragma unroll
                for (int kh = 0; kh < 2; ++kh)
                    acc[4 + mi][ni] = __builtin_amdgcn_mfma_f32_16x16x32_bf16(af[mi][kh], bf0[ni][kh], acc[4 + mi][ni], 0, 0, 0);
        __builtin_amdgcn_s_setprio(0);

        __builtin_amdgcn_s_barrier();  // protect buf cur before it is restaged
    }

    // epilogue
    if (!outf32) {
        unsigned short* O = (unsigned short*)out;
#pragma unroll
        for (int m = 0; m < 8; ++m)
#pragma unroll
            for (int n = 0; n < 4; ++n)
#pragma unroll
                for (int r = 0; r < 4; ++r) {
                    int row = row0 + wm * 128 + m * 16 + kg * 4 + r;
                    int col = col0 + wn * 64 + n * 16 + r16;
                    float bias = (col < HID) ? b0[col]
                               : (col < HID + 512 ? b1[col - HID] : b2[col - HID - 512]);
                    O[(size_t)row * N + col] = f2b(acc[m][n][r] + bias);
                }
    } else {
        float* O = (float*)out;
#pragma unroll
        for (int m = 0; m < 8; ++m)
#pragma unroll
            for (int n = 0; n < 4; ++n)
#pragma unroll
                for (int r = 0; r < 4; ++r) {
                    int row = row0 + wm * 128 + m * 16 + kg * 4 + r;
                    int col = col0 + wn * 64 + n * 16 + r16;
                    O[(size_t)row * N + col] = acc[m][n][r] + b0[col];
                }
    }
}

// ---------------- RoPE in-place on q (heads 0..35) and k (36..39) ----------------
__global__ __launch_bounds__(256) void rope_kernel(unsigned short* __restrict__ qkv,
                                                   const float* __restrict__ cos_t,
                                                   const float* __restrict__ sin_t) {
    int idx = blockIdx.x * 256 + threadIdx.x;   // SEQ*40*64 threads
    int d = idx & 63;
    int t = idx >> 6;
    int head = t % 40;
    int s = t / 40;
    int base = head < NHEAD ? head * HDIM : HID + (head - NHEAD) * HDIM;
    size_t off = (size_t)s * NQKV + base;
    float x = b2f(qkv[off + d]);
    float y = b2f(qkv[off + d + 64]);
    float c = cos_t[s * HDIM + d];
    float sn = sin_t[s * HDIM + d];
    qkv[off + d]      = f2b(x * c - y * sn);
    qkv[off + d + 64] = f2b(y * c + x * sn);
}

// ---------------- flash attention, GQA + causal + sliding window ----------------
#define KSTR 136
#define VSTR 88
#define PSTR 88
__global__ __launch_bounds__(256) void attn_kernel(const unsigned short* __restrict__ qkv,
                                                   unsigned short* __restrict__ aout)
{
    __shared__ alignas(16) unsigned short Ks[64 * KSTR];
    __shared__ alignas(16) unsigned short Vt[128 * VSTR];
    __shared__ alignas(16) unsigned short Ps[4 * 16 * PSTR];
    const int h = blockIdx.x, qb = blockIdx.y;
    const int q0 = qb * 64;
    const int kvh = h / 9;
    const int tid = threadIdx.x, wid = tid >> 6, lane = tid & 63;
    const int r16 = lane & 15, kg = lane >> 4;
    const int qbase = q0 + wid * 16;

    bf16x8 qf[4];
    {
        const unsigned short* qrow = qkv + (size_t)(qbase + r16) * NQKV + h * HDIM;
#pragma unroll
        for (int kk = 0; kk < 4; ++kk)
            qf[kk] = *(const bf16x8*)(qrow + kk * 32 + kg * 8);
    }

    f32x4 o[8] = {};
    float mrow[4], lrow[4];
#pragma unroll
    for (int r = 0; r < 4; ++r) { mrow[r] = -1e30f; lrow[r] = 0.f; }

    int lo = q0 - (WINDOW - 1); if (lo < 0) lo = 0; lo &= ~63;
    unsigned short* myP = Ps + wid * 16 * PSTR;
    const float scale = 0.08838834764831845f;

    for (int kt = lo; kt <= q0; kt += 64) {
        for (int c = tid; c < 1024; c += 256) {
            int key = c >> 4, dc = c & 15;
            const unsigned short* kp = qkv + (size_t)(kt + key) * NQKV + HID + kvh * HDIM + dc * 8;
            *(u16x8*)(Ks + key * KSTR + dc * 8) = *(const u16x8*)kp;
            const unsigned short* vp = qkv + (size_t)(kt + key) * NQKV + HID + 512 + kvh * HDIM + dc * 8;
            u16x8 vv = *(const u16x8*)vp;
#pragma unroll
            for (int j = 0; j < 8; ++j)
                Vt[(dc * 8 + j) * VSTR + key] = vv[j];
        }
        __syncthreads();

        f32x4 sc[4] = {};
#pragma unroll
        for (int t = 0; t < 4; ++t)
#pragma unroll
            for (int kk = 0; kk < 4; ++kk) {
                bf16x8 kf = *(const bf16x8*)(Ks + (t * 16 + r16) * KSTR + kk * 32 + kg * 8);
                sc[t] = __builtin_amdgcn_mfma_f32_16x16x32_bf16(qf[kk], kf, sc[t], 0, 0, 0);
            }

        float p[4][4], mt[4];
#pragma unroll
        for (int r = 0; r < 4; ++r) mt[r] = -1e30f;
#pragma unroll
        for (int t = 0; t < 4; ++t)
#pragma unroll
            for (int r = 0; r < 4; ++r) {
                int q = qbase + kg * 4 + r;
                int key = kt + t * 16 + r16;
                bool valid = (key <= q) && (q - key < WINDOW);
                float v = valid ? sc[t][r] * scale : -1e30f;
                p[t][r] = v;
                mt[r] = fmaxf(mt[r], v);
            }
#pragma unroll
        for (int mask = 1; mask <= 8; mask <<= 1)
#pragma unroll
            for (int r = 0; r < 4; ++r)
                mt[r] = fmaxf(mt[r], __shfl_xor(mt[r], mask, 64));

        float alpha[4], tsum[4];
#pragma unroll
        for (int r = 0; r < 4; ++r) {
            float mnew = fmaxf(mrow[r], mt[r]);
            alpha[r] = __expf(mrow[r] - mnew);
            mrow[r] = mnew;
            tsum[r] = 0.f;
        }
#pragma unroll
        for (int t = 0; t < 4; ++t)
#pragma unroll
            for (int r = 0; r < 4; ++r) {
                float e = __expf(p[t][r] - mrow[r]);
                p[t][r] = e;
                tsum[r] += e;
            }
#pragma unroll
        for (int mask = 1; mask <= 8; mask <<= 1)
#pragma unroll
            for (int r = 0; r < 4; ++r)
                tsum[r] += __shfl_xor(tsum[r], mask, 64);
#pragma unroll
        for (int r = 0; r < 4; ++r)
            lrow[r] = lrow[r] * alpha[r] + tsum[r];
#pragma unroll
        for (int n = 0; n < 8; ++n)
#pragma unroll
            for (int r = 0; r < 4; ++r)
                o[n][r] = o[n][r] * alpha[r];

#pragma unroll
        for (int t = 0; t < 4; ++t)
#pragma unroll
            for (int r = 0; r < 4; ++r)
                myP[(kg * 4 + r) * PSTR + t * 16 + r16] = f2b(p[t][r]);
        asm volatile("s_waitcnt lgkmcnt(0)" ::: "memory");

#pragma unroll
        for (int kc = 0; kc < 2; ++kc) {
            bf16x8 pa = *(const bf16x8*)(myP + r16 * PSTR + kc * 32 + kg * 8);
#pragma unroll
            for (int n = 0; n < 8; ++n) {
                bf16x8 vb = *(const bf16x8*)(Vt + (n * 16 + r16) * VSTR + kc * 32 + kg * 8);
                o[n] = __builtin_amdgcn_mfma_f32_16x16x32_bf16(pa, vb, o[n], 0, 0, 0);
            }
        }
        __syncthreads();
    }

#pragma unroll
    for (int n = 0; n < 8; ++n)
#pragma unroll
        for (int r = 0; r < 4; ++r) {
            int q = qbase + kg * 4 + r;
            aout[(size_t)q * HID + h * HDIM + n * 16 + r16] = f2b(o[n][r] / lrow[r]);
        }
}

extern "C" void kernel_launch(void* const* d_in, const int* in_sizes, int n_in,
                              void* d_out, int out_size, void* d_ws, size_t ws_size,
                              hipStream_t stream) {
    const float* hidden = (const float*)d_in[0];
    const float* cos_t = (const float*)d_in[2];
    const float* sin_t = (const float*)d_in[3];
    const float* q_w = (const float*)d_in[4];
    const float* q_b = (const float*)d_in[5];
    const float* k_w = (const float*)d_in[6];
    const float* k_b = (const float*)d_in[7];
    const float* v_w = (const float*)d_in[8];
    const float* v_b = (const float*)d_in[9];
    const float* o_w = (const float*)d_in[10];
    const float* o_b = (const float*)d_in[11];

    char* ws = (char*)d_ws;
    unsigned short* hbf  = (unsigned short*)ws;                   // 2048*4608 bf16
    unsigned short* attn = hbf;                                   // alias: reused after QKV GEMM
    unsigned short* wqkv = (unsigned short*)(ws + 18874368);      // 5632*4608 bf16
    unsigned short* wo   = (unsigned short*)(ws + 70778880);      // 4608*4608 bf16
    unsigned short* qkv  = (unsigned short*)(ws + 113246208);     // 2048*5632 bf16

    dim3 blk(256);
    conv_kernel<<<2048, blk, 0, stream>>>(hidden, hbf, (SEQ * HID) / 4);
    conv_kernel<<<2048, blk, 0, stream>>>(q_w, wqkv, (HID * HID) / 4);
    conv_kernel<<<2048, blk, 0, stream>>>(k_w, wqkv + (size_t)HID * HID, (512 * HID) / 4);
    conv_kernel<<<2048, blk, 0, stream>>>(v_w, wqkv + (size_t)5120 * HID, (512 * HID) / 4);
    conv_kernel<<<2048, blk, 0, stream>>>(o_w, wo, (HID * HID) / 4);

    gemm256_kernel<<<dim3(176), dim3(512), 0, stream>>>(hbf, wqkv, qkv, q_b, k_b, v_b, NQKV, HID, 22, 0);
    rope_kernel<<<(SEQ * 40 * 64) / 256, blk, 0, stream>>>(qkv, cos_t, sin_t);
    attn_kernel<<<dim3(NHEAD, SEQ / 64), blk, 0, stream>>>(qkv, attn);
    gemm256_kernel<<<dim3(144), dim3(512), 0, stream>>>(attn, wo, d_out, o_b, nullptr, nullptr, HID, HID, 18, 1);
}

// Round 4
// 449.164 us; speedup vs baseline: 1.5615x; 1.1911x over previous
//
#include <hip/hip_runtime.h>
#include <stdint.h>

typedef __attribute__((ext_vector_type(8))) __bf16 bf16x8;
typedef __attribute__((ext_vector_type(4))) float f32x4;
typedef __attribute__((ext_vector_type(8))) unsigned short u16x8;
typedef __attribute__((ext_vector_type(4))) unsigned short u16x4;

#define SEQ 2048
#define HID 4608
#define NQKV 5632   // 4608 q + 512 k + 512 v
#define NHEAD 36
#define NKVH 4
#define HDIM 128
#define WINDOW 1024

__device__ __forceinline__ unsigned short f2b(float f) {
    unsigned u = __builtin_bit_cast(unsigned, f);
    u += 0x7fffu + ((u >> 16) & 1u);
    return (unsigned short)(u >> 16);
}
__device__ __forceinline__ float b2f(unsigned short h) {
    unsigned u = ((unsigned)h) << 16;
    return __builtin_bit_cast(float, u);
}

#define GLD16(gp, lp) __builtin_amdgcn_global_load_lds( \
    (const __attribute__((address_space(1))) void*)(gp), \
    (__attribute__((address_space(3))) void*)(lp), 16, 0, 0)

#define VMCNT8() asm volatile("s_waitcnt vmcnt(8)" ::: "memory")
#define VMCNT0() asm volatile("s_waitcnt vmcnt(0)" ::: "memory")
// HW barrier + COMPILER memory fence (raw builtin is IntrNoMem -> loads may hoist past it)
#define BARRIER() asm volatile("s_barrier" ::: "memory")

// ---------------- f32 -> bf16 convert ----------------
__global__ __launch_bounds__(256) void conv_kernel(const float* __restrict__ src,
                                                   unsigned short* __restrict__ dst, int n4) {
    int stride = gridDim.x * blockDim.x;
    for (int i = blockIdx.x * blockDim.x + threadIdx.x; i < n4; i += stride) {
        float4 v = ((const float4*)src)[i];
        ushort4 o;
        o.x = f2b(v.x); o.y = f2b(v.y); o.z = f2b(v.z); o.w = f2b(v.w);
        ((ushort4*)dst)[i] = o;
    }
}

// ---------------- GEMM 256x256 tile, BK=64, 8 waves, phase-split ----------------
__global__ __launch_bounds__(512, 2) void gemm256_kernel(
    const unsigned short* __restrict__ A,
    const unsigned short* __restrict__ W,
    void* __restrict__ out,
    const float* __restrict__ b0, const float* __restrict__ b1, const float* __restrict__ b2,
    int N, int K, int GX, int outf32)
{
    __shared__ alignas(16) unsigned short lds[2][2][256 * 64];

    const int tid = threadIdx.x;
    const int w = tid >> 6, lane = tid & 63;
    const int r16 = lane & 15, kg = lane >> 4;
    const int wm = w >> 2, wn = w & 3;

    const int cpx = gridDim.x >> 3;
    const int o = blockIdx.x;
    const int id = (o & 7) * cpx + (o >> 3);
    const int bx = id % GX, by = id / GX;
    const int row0 = by * 256, col0 = bx * 256;

    const int lr = lane >> 3;
    const int lc = lane & 7;
    const int cg = lc ^ lr;
    const unsigned short* aP[4];
    const unsigned short* bP[4];
#pragma unroll
    for (int j = 0; j < 4; ++j) {
        const int L = w * 4 + j;
        aP[j] = A + (size_t)(row0 + L * 8 + lr) * K + cg * 8;
        bP[j] = W + (size_t)(col0 + L * 8 + lr) * K + cg * 8;
    }

    const int NT = K >> 6;
    f32x4 acc[8][4] = {};

#pragma unroll
    for (int j = 0; j < 4; ++j) GLD16(aP[j], (char*)&lds[0][0][0] + (w * 4 + j) * 1024);
#pragma unroll
    for (int j = 0; j < 4; ++j) GLD16(bP[j], (char*)&lds[0][1][0] + (w * 4 + j) * 1024);
#pragma unroll
    for (int j = 0; j < 4; ++j) { aP[j] += 64; bP[j] += 64; }

    const int swz = r16 & 7;
    for (int t = 0; t < NT; ++t) {
        const int cur = t & 1;
        if (t + 1 < NT) {
            const int nxt = cur ^ 1;
#pragma unroll
            for (int j = 0; j < 4; ++j) GLD16(aP[j], (char*)&lds[nxt][0][0] + (w * 4 + j) * 1024);
#pragma unroll
            for (int j = 0; j < 4; ++j) GLD16(bP[j], (char*)&lds[nxt][1][0] + (w * 4 + j) * 1024);
#pragma unroll
            for (int j = 0; j < 4; ++j) { aP[j] += 64; bP[j] += 64; }
            VMCNT8();
        } else {
            VMCNT0();
        }
        BARRIER();

        const unsigned short* As_ = &lds[cur][0][0];
        const unsigned short* Bs_ = &lds[cur][1][0];

        bf16x8 af[4][2], bf0[2][2], bf1[2][2];
#pragma unroll
        for (int ni = 0; ni < 2; ++ni)
#pragma unroll
            for (int kh = 0; kh < 2; ++kh) {
                int rb0 = wn * 64 + ni * 16 + r16;
                int rb1 = wn * 64 + 32 + ni * 16 + r16;
                bf0[ni][kh] = *(const bf16x8*)(Bs_ + rb0 * 64 + ((kh * 4 + kg) ^ swz) * 8);
                bf1[ni][kh] = *(const bf16x8*)(Bs_ + rb1 * 64 + ((kh * 4 + kg) ^ swz) * 8);
            }
#pragma unroll
        for (int mi = 0; mi < 4; ++mi)
#pragma unroll
            for (int kh = 0; kh < 2; ++kh) {
                int ra = wm * 128 + mi * 16 + r16;
                af[mi][kh] = *(const bf16x8*)(As_ + ra * 64 + ((kh * 4 + kg) ^ swz) * 8);
            }

        __builtin_amdgcn_s_setprio(1);
#pragma unroll
        for (int mi = 0; mi < 4; ++mi)
#pragma unroll
            for (int ni = 0; ni < 2; ++ni)
#pragma unroll
                for (int kh = 0; kh < 2; ++kh)
                    acc[mi][ni] = __builtin_amdgcn_mfma_f32_16x16x32_bf16(af[mi][kh], bf0[ni][kh], acc[mi][ni], 0, 0, 0);
        __builtin_amdgcn_s_setprio(0);
        __builtin_amdgcn_s_setprio(1);
#pragma unroll
        for (int mi = 0; mi < 4; ++mi)
#pragma unroll
            for (int ni = 0; ni < 2; ++ni)
#pragma unroll
                for (int kh = 0; kh < 2; ++kh)
                    acc[mi][2 + ni] = __builtin_amdgcn_mfma_f32_16x16x32_bf16(af[mi][kh], bf1[ni][kh], acc[mi][2 + ni], 0, 0, 0);
        __builtin_amdgcn_s_setprio(0);
#pragma unroll
        for (int mi = 0; mi < 4; ++mi)
#pragma unroll
            for (int kh = 0; kh < 2; ++kh) {
                int ra = wm * 128 + 64 + mi * 16 + r16;
                af[mi][kh] = *(const bf16x8*)(As_ + ra * 64 + ((kh * 4 + kg) ^ swz) * 8);
            }
        __builtin_amdgcn_s_setprio(1);
#pragma unroll
        for (int mi = 0; mi < 4; ++mi)
#pragma unroll
            for (int ni = 0; ni < 2; ++ni)
#pragma unroll
                for (int kh = 0; kh < 2; ++kh)
                    acc[4 + mi][2 + ni] = __builtin_amdgcn_mfma_f32_16x16x32_bf16(af[mi][kh], bf1[ni][kh], acc[4 + mi][2 + ni], 0, 0, 0);
        __builtin_amdgcn_s_setprio(0);
        __builtin_amdgcn_s_setprio(1);
#pragma unroll
        for (int mi = 0; mi < 4; ++mi)
#pragma unroll
            for (int ni = 0; ni < 2; ++ni)
#pragma unroll
                for (int kh = 0; kh < 2; ++kh)
                    acc[4 + mi][ni] = __builtin_amdgcn_mfma_f32_16x16x32_bf16(af[mi][kh], bf0[ni][kh], acc[4 + mi][ni], 0, 0, 0);
        __builtin_amdgcn_s_setprio(0);

        BARRIER();
    }

    if (!outf32) {
        unsigned short* O = (unsigned short*)out;
#pragma unroll
        for (int m = 0; m < 8; ++m)
#pragma unroll
            for (int n = 0; n < 4; ++n)
#pragma unroll
                for (int r = 0; r < 4; ++r) {
                    int row = row0 + wm * 128 + m * 16 + kg * 4 + r;
                    int col = col0 + wn * 64 + n * 16 + r16;
                    float bias = (col < HID) ? b0[col]
                               : (col < HID + 512 ? b1[col - HID] : b2[col - HID - 512]);
                    O[(size_t)row * N + col] = f2b(acc[m][n][r] + bias);
                }
    } else {
        float* O = (float*)out;
#pragma unroll
        for (int m = 0; m < 8; ++m)
#pragma unroll
            for (int n = 0; n < 4; ++n)
#pragma unroll
                for (int r = 0; r < 4; ++r) {
                    int row = row0 + wm * 128 + m * 16 + kg * 4 + r;
                    int col = col0 + wn * 64 + n * 16 + r16;
                    O[(size_t)row * N + col] = acc[m][n][r] + b0[col];
                }
    }
}

// ---------------- RoPE in-place on q (heads 0..35) and k (36..39) ----------------
__global__ __launch_bounds__(256) void rope_kernel(unsigned short* __restrict__ qkv,
                                                   const float* __restrict__ cos_t,
                                                   const float* __restrict__ sin_t) {
    int idx = blockIdx.x * 256 + threadIdx.x;
    int d = idx & 63;
    int t = idx >> 6;
    int head = t % 40;
    int s = t / 40;
    int base = head < NHEAD ? head * HDIM : HID + (head - NHEAD) * HDIM;
    size_t off = (size_t)s * NQKV + base;
    float x = b2f(qkv[off + d]);
    float y = b2f(qkv[off + d + 64]);
    float c = cos_t[s * HDIM + d];
    float sn = sin_t[s * HDIM + d];
    qkv[off + d]      = f2b(x * c - y * sn);
    qkv[off + d + 64] = f2b(y * c + x * sn);
}

// ---------------- V transpose: qkv V block -> vtg[kvh][128][2048] ----------------
__global__ __launch_bounds__(256) void vtrans_kernel(const unsigned short* __restrict__ qkv,
                                                     unsigned short* __restrict__ vtg) {
    __shared__ unsigned short tile[32][36];
    const int s0 = blockIdx.x * 32, d0 = blockIdx.y * 32, kvh = blockIdx.z;
    const int lid = threadIdx.x;
    {
        int sl = lid >> 3, dc = (lid & 7) * 4;
        u16x4 v = *(const u16x4*)(qkv + (size_t)(s0 + sl) * NQKV + HID + 512 + kvh * HDIM + d0 + dc);
#pragma unroll
        for (int i = 0; i < 4; ++i) tile[sl][dc + i] = v[i];
    }
    __syncthreads();
    {
        int dl = lid >> 3, sc = (lid & 7) * 4;
        u16x4 v;
#pragma unroll
        for (int i = 0; i < 4; ++i) v[i] = tile[sc + i][dl];
        *(u16x4*)(vtg + (size_t)kvh * HDIM * SEQ + (size_t)(d0 + dl) * SEQ + s0 + sc) = v;
    }
}

// ---------------- flash attention, GQA + causal + sliding window ----------------
#define KSTR 136   // Ks row stride (u16): 272B = 68 dw ≡ 4 mod 32 -> 2-way free
#define VSTR 72    // Vt row stride (u16): 144B = 36 dw ≡ 4 mod 32 -> 2-way free
#define PSTR 88
__global__ __launch_bounds__(256) void attn_kernel(const unsigned short* __restrict__ qkv,
                                                   const unsigned short* __restrict__ vtg,
                                                   unsigned short* __restrict__ aout)
{
    __shared__ alignas(16) unsigned short Ks[64 * KSTR];
    __shared__ alignas(16) unsigned short Vt[128 * VSTR];
    __shared__ alignas(16) unsigned short Ps[4 * 16 * PSTR];
    const int h = blockIdx.x, qb = blockIdx.y;
    const int q0 = qb * 64;
    const int kvh = h / 9;
    const int tid = threadIdx.x, wid = tid >> 6, lane = tid & 63;
    const int r16 = lane & 15, kg = lane >> 4;
    const int qbase = q0 + wid * 16;
    const unsigned short* vsrc = vtg + (size_t)kvh * HDIM * SEQ;

    bf16x8 qf[4];
    {
        const unsigned short* qrow = qkv + (size_t)(qbase + r16) * NQKV + h * HDIM;
#pragma unroll
        for (int kk = 0; kk < 4; ++kk)
            qf[kk] = *(const bf16x8*)(qrow + kk * 32 + kg * 8);
    }

    f32x4 o[8] = {};
    float mrow[4], lrow[4];
#pragma unroll
    for (int r = 0; r < 4; ++r) { mrow[r] = -1e30f; lrow[r] = 0.f; }

    int lo = q0 - (WINDOW - 1); if (lo < 0) lo = 0; lo &= ~63;
    unsigned short* myP = Ps + wid * 16 * PSTR;
    const float scale = 0.08838834764831845f;

    for (int kt = lo; kt <= q0; kt += 64) {
        // stage K[64][128] rows and V^T[128][64] rows — both fully vectorized
        for (int c = tid; c < 1024; c += 256) {
            int key = c >> 4, dc = c & 15;
            const unsigned short* kp = qkv + (size_t)(kt + key) * NQKV + HID + kvh * HDIM + dc * 8;
            *(u16x8*)(Ks + key * KSTR + dc * 8) = *(const u16x8*)kp;
            int d = c >> 3, k8 = (c & 7) * 8;
            *(u16x8*)(Vt + d * VSTR + k8) = *(const u16x8*)(vsrc + (size_t)d * SEQ + kt + k8);
        }
        __syncthreads();

        f32x4 sc[4] = {};
#pragma unroll
        for (int t = 0; t < 4; ++t)
#pragma unroll
            for (int kk = 0; kk < 4; ++kk) {
                bf16x8 kf = *(const bf16x8*)(Ks + (t * 16 + r16) * KSTR + kk * 32 + kg * 8);
                sc[t] = __builtin_amdgcn_mfma_f32_16x16x32_bf16(qf[kk], kf, sc[t], 0, 0, 0);
            }

        float p[4][4], mt[4];
#pragma unroll
        for (int r = 0; r < 4; ++r) mt[r] = -1e30f;
#pragma unroll
        for (int t = 0; t < 4; ++t)
#pragma unroll
            for (int r = 0; r < 4; ++r) {
                int q = qbase + kg * 4 + r;
                int key = kt + t * 16 + r16;
                bool valid = (key <= q) && (q - key < WINDOW);
                float v = valid ? sc[t][r] * scale : -1e30f;
                p[t][r] = v;
                mt[r] = fmaxf(mt[r], v);
            }
#pragma unroll
        for (int mask = 1; mask <= 8; mask <<= 1)
#pragma unroll
            for (int r = 0; r < 4; ++r)
                mt[r] = fmaxf(mt[r], __shfl_xor(mt[r], mask, 64));

        float alpha[4], tsum[4];
#pragma unroll
        for (int r = 0; r < 4; ++r) {
            float mnew = fmaxf(mrow[r], mt[r]);
            alpha[r] = __expf(mrow[r] - mnew);
            mrow[r] = mnew;
            tsum[r] = 0.f;
        }
#pragma unroll
        for (int t = 0; t < 4; ++t)
#pragma unroll
            for (int r = 0; r < 4; ++r) {
                float e = __expf(p[t][r] - mrow[r]);
                p[t][r] = e;
                tsum[r] += e;
            }
#pragma unroll
        for (int mask = 1; mask <= 8; mask <<= 1)
#pragma unroll
            for (int r = 0; r < 4; ++r)
                tsum[r] += __shfl_xor(tsum[r], mask, 64);
#pragma unroll
        for (int r = 0; r < 4; ++r)
            lrow[r] = lrow[r] * alpha[r] + tsum[r];
#pragma unroll
        for (int n = 0; n < 8; ++n)
#pragma unroll
            for (int r = 0; r < 4; ++r)
                o[n][r] = o[n][r] * alpha[r];

#pragma unroll
        for (int t = 0; t < 4; ++t)
#pragma unroll
            for (int r = 0; r < 4; ++r)
                myP[(kg * 4 + r) * PSTR + t * 16 + r16] = f2b(p[t][r]);
        asm volatile("s_waitcnt lgkmcnt(0)" ::: "memory");

#pragma unroll
        for (int kc = 0; kc < 2; ++kc) {
            bf16x8 pa = *(const bf16x8*)(myP + r16 * PSTR + kc * 32 + kg * 8);
#pragma unroll
            for (int n = 0; n < 8; ++n) {
                bf16x8 vb = *(const bf16x8*)(Vt + (n * 16 + r16) * VSTR + kc * 32 + kg * 8);
                o[n] = __builtin_amdgcn_mfma_f32_16x16x32_bf16(pa, vb, o[n], 0, 0, 0);
            }
        }
        __syncthreads();
    }

#pragma unroll
    for (int n = 0; n < 8; ++n)
#pragma unroll
        for (int r = 0; r < 4; ++r) {
            int q = qbase + kg * 4 + r;
            aout[(size_t)q * HID + h * HDIM + n * 16 + r16] = f2b(o[n][r] / lrow[r]);
        }
}

extern "C" void kernel_launch(void* const* d_in, const int* in_sizes, int n_in,
                              void* d_out, int out_size, void* d_ws, size_t ws_size,
                              hipStream_t stream) {
    const float* hidden = (const float*)d_in[0];
    const float* cos_t = (const float*)d_in[2];
    const float* sin_t = (const float*)d_in[3];
    const float* q_w = (const float*)d_in[4];
    const float* q_b = (const float*)d_in[5];
    const float* k_w = (const float*)d_in[6];
    const float* k_b = (const float*)d_in[7];
    const float* v_w = (const float*)d_in[8];
    const float* v_b = (const float*)d_in[9];
    const float* o_w = (const float*)d_in[10];
    const float* o_b = (const float*)d_in[11];

    char* ws = (char*)d_ws;
    unsigned short* hbf  = (unsigned short*)ws;                   // 2048*4608 bf16
    unsigned short* attn = hbf;                                   // alias: reused after QKV GEMM
    unsigned short* wqkv = (unsigned short*)(ws + 18874368);      // 5632*4608 bf16 (dead after QKV GEMM)
    unsigned short* vtg  = wqkv;                                  // alias: V^T [4][128][2048]
    unsigned short* wo   = (unsigned short*)(ws + 70778880);      // 4608*4608 bf16
    unsigned short* qkv  = (unsigned short*)(ws + 113246208);     // 2048*5632 bf16

    dim3 blk(256);
    conv_kernel<<<2048, blk, 0, stream>>>(hidden, hbf, (SEQ * HID) / 4);
    conv_kernel<<<2048, blk, 0, stream>>>(q_w, wqkv, (HID * HID) / 4);
    conv_kernel<<<2048, blk, 0, stream>>>(k_w, wqkv + (size_t)HID * HID, (512 * HID) / 4);
    conv_kernel<<<2048, blk, 0, stream>>>(v_w, wqkv + (size_t)5120 * HID, (512 * HID) / 4);
    conv_kernel<<<2048, blk, 0, stream>>>(o_w, wo, (HID * HID) / 4);

    gemm256_kernel<<<dim3(176), dim3(512), 0, stream>>>(hbf, wqkv, qkv, q_b, k_b, v_b, NQKV, HID, 22, 0);
    rope_kernel<<<(SEQ * 40 * 64) / 256, blk, 0, stream>>>(qkv, cos_t, sin_t);
    vtrans_kernel<<<dim3(SEQ / 32, HDIM / 32, NKVH), blk, 0, stream>>>(qkv, vtg);
    attn_kernel<<<dim3(NHEAD, SEQ / 64), blk, 0, stream>>>(qkv, vtg, attn);
    gemm256_kernel<<<dim3(144), dim3(512), 0, stream>>>(attn, wo, d_out, o_b, nullptr, nullptr, HID, HID, 18, 1);
}

// Round 5
// 444.502 us; speedup vs baseline: 1.5779x; 1.0105x over previous
//
#include <hip/hip_runtime.h>
#include <stdint.h>

typedef __attribute__((ext_vector_type(8))) __bf16 bf16x8;
typedef __attribute__((ext_vector_type(4))) float f32x4;
typedef __attribute__((ext_vector_type(8))) unsigned short u16x8;
typedef __attribute__((ext_vector_type(4))) unsigned short u16x4;

#define SEQ 2048
#define HID 4608
#define NQKV 5632   // 4608 q + 512 k + 512 v
#define NHEAD 36
#define NKVH 4
#define HDIM 128
#define WINDOW 1024

__device__ __forceinline__ unsigned short f2b(float f) {
    unsigned u = __builtin_bit_cast(unsigned, f);
    u += 0x7fffu + ((u >> 16) & 1u);
    return (unsigned short)(u >> 16);
}
__device__ __forceinline__ float b2f(unsigned short h) {
    unsigned u = ((unsigned)h) << 16;
    return __builtin_bit_cast(float, u);
}

#define GLD16(gp, lp) __builtin_amdgcn_global_load_lds( \
    (const __attribute__((address_space(1))) void*)(gp), \
    (__attribute__((address_space(3))) void*)(lp), 16, 0, 0)

#define VMCNT8() asm volatile("s_waitcnt vmcnt(8)" ::: "memory")
#define VMCNT4() asm volatile("s_waitcnt vmcnt(4)" ::: "memory")
#define VMCNT0() asm volatile("s_waitcnt vmcnt(0)" ::: "memory")
// HW barrier + COMPILER memory fence (raw builtin is IntrNoMem -> loads may hoist past it)
#define BARRIER() asm volatile("s_barrier" ::: "memory")

// ---------------- f32 -> bf16 convert ----------------
__global__ __launch_bounds__(256) void conv_kernel(const float* __restrict__ src,
                                                   unsigned short* __restrict__ dst, int n4) {
    int stride = gridDim.x * blockDim.x;
    for (int i = blockIdx.x * blockDim.x + threadIdx.x; i < n4; i += stride) {
        float4 v = ((const float4*)src)[i];
        ushort4 o;
        o.x = f2b(v.x); o.y = f2b(v.y); o.z = f2b(v.z); o.w = f2b(v.w);
        ((ushort4*)dst)[i] = o;
    }
}

// ---------------- GEMM 256x256 tile, BK=64, 8 waves, true 8-phase pipeline ----------------
// C[M,N] = A[M,K] @ W[N,K]^T + bias.
// Iteration processes K-tiles (2i)->slot0, (2i+1)->slot1; stages pair i+1 in-place:
//   ph3:B0h0 ph4:A0h0 ph5:A0h1 ph6:B0h1 ph7:B1h0+B1h1 ph8:A1h0+A1h1
// waits: vmcnt(4)@ph4 (drains prev ph8 A(s1) before ph5 reads), vmcnt(8)@ph8 (drains s0).
__global__ __launch_bounds__(512, 2) void gemm256_kernel(
    const unsigned short* __restrict__ A,
    const unsigned short* __restrict__ W,
    void* __restrict__ out,
    const float* __restrict__ b0, const float* __restrict__ b1, const float* __restrict__ b2,
    int N, int K, int GX, int outf32)
{
    __shared__ alignas(16) unsigned short ldsA[2][256 * 64];
    __shared__ alignas(16) unsigned short ldsB[2][256 * 64];

    const int tid = threadIdx.x;
    const int w = tid >> 6, lane = tid & 63;
    const int r16 = lane & 15, kg = lane >> 4;
    const int wm = w >> 2, wn = w & 3;          // 2M x 4N waves

    // T1: bijective XCD swizzle (grids here are multiples of 8)
    const int cpx = gridDim.x >> 3;
    const int o = blockIdx.x;
    const int id = (o & 7) * cpx + (o >> 3);
    const int bx = id % GX, by = id / GX;
    const int row0 = by * 256, col0 = bx * 256;

    // staging geometry: half-tile = 128 rows x 64 k of one matrix; 2 gloads/thread/half
    const int lr = lane >> 3;          // row within 8-row group
    const int lc = lane & 7;           // physical 16B chunk slot
    const int cg = lc ^ lr;            // pre-swizzled global chunk (rule #21)
    const unsigned short* Abase = A + (size_t)row0 * K;
    const unsigned short* Wbase = W + (size_t)col0 * K;

    // stage one half (hf) of matrix into slot: kb = K-offset of the tile
    auto STG = [&](const unsigned short* Mat, unsigned short* ldsSlot, int hf, int kb) {
#pragma unroll
        for (int j = 0; j < 2; ++j) {
            int row = hf * 128 + (w * 2 + j) * 8 + lr;
            GLD16(Mat + (size_t)row * K + kb + cg * 8,
                  (char*)ldsSlot + hf * 16384 + (w * 2 + j) * 1024);
        }
    };

    const int NITER = K >> 7;          // pairs of 64-wide K-tiles
    f32x4 acc[8][4] = {};
    const int swz = r16 & 7;

    bf16x8 af[4][2], bfA[2][2], bfB[2][2];

#define DSR_A(mh, Sl) \
_Pragma("unroll") for (int mi = 0; mi < 4; ++mi) \
_Pragma("unroll") for (int kh = 0; kh < 2; ++kh) \
    af[mi][kh] = *(const bf16x8*)((Sl) + (wm * 128 + (mh) * 64 + mi * 16 + r16) * 64 + ((kh * 4 + kg) ^ swz) * 8);
#define DSR_B(nh, Sl, BF) \
_Pragma("unroll") for (int ni = 0; ni < 2; ++ni) \
_Pragma("unroll") for (int kh = 0; kh < 2; ++kh) \
    BF[ni][kh] = *(const bf16x8*)((Sl) + (wn * 64 + (nh) * 32 + ni * 16 + r16) * 64 + ((kh * 4 + kg) ^ swz) * 8);
#define MFMA_Q(mh, nh, BF) \
    __builtin_amdgcn_s_setprio(1); \
_Pragma("unroll") for (int mi = 0; mi < 4; ++mi) \
_Pragma("unroll") for (int ni = 0; ni < 2; ++ni) \
_Pragma("unroll") for (int kh = 0; kh < 2; ++kh) \
    acc[(mh) * 4 + mi][(nh) * 2 + ni] = __builtin_amdgcn_mfma_f32_16x16x32_bf16(af[mi][kh], BF[ni][kh], acc[(mh) * 4 + mi][(nh) * 2 + ni], 0, 0, 0); \
    __builtin_amdgcn_s_setprio(0);

    // prologue: stage pair 0 fully (16 loads/thread), drain, barrier
    STG(Abase, ldsA[0], 0, 0);  STG(Abase, ldsA[0], 1, 0);
    STG(Wbase, ldsB[0], 0, 0);  STG(Wbase, ldsB[0], 1, 0);
    STG(Abase, ldsA[1], 0, 64); STG(Abase, ldsA[1], 1, 64);
    STG(Wbase, ldsB[1], 0, 64); STG(Wbase, ldsB[1], 1, 64);
    VMCNT0();
    BARRIER();

    for (int i = 0; i < NITER; ++i) {
        const unsigned short* A0 = ldsA[0];
        const unsigned short* B0 = ldsB[0];
        const unsigned short* A1 = ldsA[1];
        const unsigned short* B1 = ldsB[1];
        const bool st = (i + 1 < NITER);
        const int kb0 = (i + 1) * 128;       // next pair, slot0 tile
        const int kb1 = kb0 + 64;            // next pair, slot1 tile

        // ---- phase 1: dsr afh0(t0)+bfnh0(t0); mfma q(0,0) t0
        DSR_A(0, A0); DSR_B(0, B0, bfA);
        BARRIER();
        MFMA_Q(0, 0, bfA);
        BARRIER();
        // ---- phase 2: dsr bfnh1(t0); mfma q(0,1) t0
        DSR_B(1, B0, bfB);
        BARRIER();
        MFMA_Q(0, 1, bfB);
        BARRIER();
        // ---- phase 3: dsr afh1(t0); stage B0h0'; mfma q(1,1) t0
        DSR_A(1, A0);
        if (st) STG(Wbase, ldsB[0], 0, kb0);
        BARRIER();
        MFMA_Q(1, 1, bfB);
        BARRIER();
        // ---- phase 4: stage A0h0'; vmcnt; mfma q(1,0) t0
        if (st) { STG(Abase, ldsA[0], 0, kb0); VMCNT4(); } else { VMCNT0(); }
        BARRIER();
        MFMA_Q(1, 0, bfA);
        BARRIER();
        // ---- phase 5: dsr afh0(t1)+bfnh0(t1); stage A0h1'; mfma q(0,0) t1
        DSR_A(0, A1); DSR_B(0, B1, bfA);
        if (st) STG(Abase, ldsA[0], 1, kb0);
        BARRIER();
        MFMA_Q(0, 0, bfA);
        BARRIER();
        // ---- phase 6: dsr bfnh1(t1); stage B0h1'; mfma q(0,1) t1
        DSR_B(1, B1, bfB);
        if (st) STG(Wbase, ldsB[0], 1, kb0);
        BARRIER();
        MFMA_Q(0, 1, bfB);
        BARRIER();
        // ---- phase 7: dsr afh1(t1); stage B1h0'+B1h1'; mfma q(1,1) t1
        DSR_A(1, A1);
        if (st) { STG(Wbase, ldsB[1], 0, kb1); STG(Wbase, ldsB[1], 1, kb1); }
        BARRIER();
        MFMA_Q(1, 1, bfB);
        BARRIER();
        // ---- phase 8: stage A1h0'+A1h1'; vmcnt(8); mfma q(1,0) t1
        if (st) { STG(Abase, ldsA[1], 0, kb1); STG(Abase, ldsA[1], 1, kb1); VMCNT8(); }
        BARRIER();
        MFMA_Q(1, 0, bfA);
        BARRIER();
    }

    if (!outf32) {
        unsigned short* O = (unsigned short*)out;
#pragma unroll
        for (int m = 0; m < 8; ++m)
#pragma unroll
            for (int n = 0; n < 4; ++n)
#pragma unroll
                for (int r = 0; r < 4; ++r) {
                    int row = row0 + wm * 128 + m * 16 + kg * 4 + r;
                    int col = col0 + wn * 64 + n * 16 + r16;
                    float bias = (col < HID) ? b0[col]
                               : (col < HID + 512 ? b1[col - HID] : b2[col - HID - 512]);
                    O[(size_t)row * N + col] = f2b(acc[m][n][r] + bias);
                }
    } else {
        float* O = (float*)out;
#pragma unroll
        for (int m = 0; m < 8; ++m)
#pragma unroll
            for (int n = 0; n < 4; ++n)
#pragma unroll
                for (int r = 0; r < 4; ++r) {
                    int row = row0 + wm * 128 + m * 16 + kg * 4 + r;
                    int col = col0 + wn * 64 + n * 16 + r16;
                    O[(size_t)row * N + col] = acc[m][n][r] + b0[col];
                }
    }
#undef DSR_A
#undef DSR_B
#undef MFMA_Q
}

// ---------------- RoPE in-place on q (heads 0..35) and k (36..39) ----------------
__global__ __launch_bounds__(256) void rope_kernel(unsigned short* __restrict__ qkv,
                                                   const float* __restrict__ cos_t,
                                                   const float* __restrict__ sin_t) {
    int idx = blockIdx.x * 256 + threadIdx.x;
    int d = idx & 63;
    int t = idx >> 6;
    int head = t % 40;
    int s = t / 40;
    int base = head < NHEAD ? head * HDIM : HID + (head - NHEAD) * HDIM;
    size_t off = (size_t)s * NQKV + base;
    float x = b2f(qkv[off + d]);
    float y = b2f(qkv[off + d + 64]);
    float c = cos_t[s * HDIM + d];
    float sn = sin_t[s * HDIM + d];
    qkv[off + d]      = f2b(x * c - y * sn);
    qkv[off + d + 64] = f2b(y * c + x * sn);
}

// ---------------- V transpose: qkv V block -> vtg[kvh][128][2048] ----------------
__global__ __launch_bounds__(256) void vtrans_kernel(const unsigned short* __restrict__ qkv,
                                                     unsigned short* __restrict__ vtg) {
    __shared__ unsigned short tile[32][36];
    const int s0 = blockIdx.x * 32, d0 = blockIdx.y * 32, kvh = blockIdx.z;
    const int lid = threadIdx.x;
    {
        int sl = lid >> 3, dc = (lid & 7) * 4;
        u16x4 v = *(const u16x4*)(qkv + (size_t)(s0 + sl) * NQKV + HID + 512 + kvh * HDIM + d0 + dc);
#pragma unroll
        for (int i = 0; i < 4; ++i) tile[sl][dc + i] = v[i];
    }
    __syncthreads();
    {
        int dl = lid >> 3, sc = (lid & 7) * 4;
        u16x4 v;
#pragma unroll
        for (int i = 0; i < 4; ++i) v[i] = tile[sc + i][dl];
        *(u16x4*)(vtg + (size_t)kvh * HDIM * SEQ + (size_t)(d0 + dl) * SEQ + s0 + sc) = v;
    }
}

// ---------------- flash attention, GQA + causal + sliding window ----------------
#define KSTR 136   // Ks row stride (u16): 272B = 68 dw ≡ 4 mod 32 -> 2-way free
#define VSTR 72    // Vt row stride (u16): 144B = 36 dw ≡ 4 mod 32 -> 2-way free
#define PSTR 88
__global__ __launch_bounds__(256) void attn_kernel(const unsigned short* __restrict__ qkv,
                                                   const unsigned short* __restrict__ vtg,
                                                   unsigned short* __restrict__ aout)
{
    __shared__ alignas(16) unsigned short Ks[64 * KSTR];
    __shared__ alignas(16) unsigned short Vt[128 * VSTR];
    __shared__ alignas(16) unsigned short Ps[4 * 16 * PSTR];
    const int h = blockIdx.x, qb = blockIdx.y;
    const int q0 = qb * 64;
    const int kvh = h / 9;
    const int tid = threadIdx.x, wid = tid >> 6, lane = tid & 63;
    const int r16 = lane & 15, kg = lane >> 4;
    const int qbase = q0 + wid * 16;
    const unsigned short* vsrc = vtg + (size_t)kvh * HDIM * SEQ;

    bf16x8 qf[4];
    {
        const unsigned short* qrow = qkv + (size_t)(qbase + r16) * NQKV + h * HDIM;
#pragma unroll
        for (int kk = 0; kk < 4; ++kk)
            qf[kk] = *(const bf16x8*)(qrow + kk * 32 + kg * 8);
    }

    f32x4 o[8] = {};
    float mrow[4], lrow[4];
#pragma unroll
    for (int r = 0; r < 4; ++r) { mrow[r] = -1e30f; lrow[r] = 0.f; }

    int lo = q0 - (WINDOW - 1); if (lo < 0) lo = 0; lo &= ~63;
    unsigned short* myP = Ps + wid * 16 * PSTR;
    const float scale = 0.08838834764831845f;

    for (int kt = lo; kt <= q0; kt += 64) {
        for (int c = tid; c < 1024; c += 256) {
            int key = c >> 4, dc = c & 15;
            const unsigned short* kp = qkv + (size_t)(kt + key) * NQKV + HID + kvh * HDIM + dc * 8;
            *(u16x8*)(Ks + key * KSTR + dc * 8) = *(const u16x8*)kp;
            int d = c >> 3, k8 = (c & 7) * 8;
            *(u16x8*)(Vt + d * VSTR + k8) = *(const u16x8*)(vsrc + (size_t)d * SEQ + kt + k8);
        }
        __syncthreads();

        f32x4 sc[4] = {};
#pragma unroll
        for (int t = 0; t < 4; ++t)
#pragma unroll
            for (int kk = 0; kk < 4; ++kk) {
                bf16x8 kf = *(const bf16x8*)(Ks + (t * 16 + r16) * KSTR + kk * 32 + kg * 8);
                sc[t] = __builtin_amdgcn_mfma_f32_16x16x32_bf16(qf[kk], kf, sc[t], 0, 0, 0);
            }

        float p[4][4], mt[4];
#pragma unroll
        for (int r = 0; r < 4; ++r) mt[r] = -1e30f;
#pragma unroll
        for (int t = 0; t < 4; ++t)
#pragma unroll
            for (int r = 0; r < 4; ++r) {
                int q = qbase + kg * 4 + r;
                int key = kt + t * 16 + r16;
                bool valid = (key <= q) && (q - key < WINDOW);
                float v = valid ? sc[t][r] * scale : -1e30f;
                p[t][r] = v;
                mt[r] = fmaxf(mt[r], v);
            }
#pragma unroll
        for (int mask = 1; mask <= 8; mask <<= 1)
#pragma unroll
            for (int r = 0; r < 4; ++r)
                mt[r] = fmaxf(mt[r], __shfl_xor(mt[r], mask, 64));

        float alpha[4], tsum[4];
#pragma unroll
        for (int r = 0; r < 4; ++r) {
            float mnew = fmaxf(mrow[r], mt[r]);
            alpha[r] = __expf(mrow[r] - mnew);
            mrow[r] = mnew;
            tsum[r] = 0.f;
        }
#pragma unroll
        for (int t = 0; t < 4; ++t)
#pragma unroll
            for (int r = 0; r < 4; ++r) {
                float e = __expf(p[t][r] - mrow[r]);
                p[t][r] = e;
                tsum[r] += e;
            }
#pragma unroll
        for (int mask = 1; mask <= 8; mask <<= 1)
#pragma unroll
            for (int r = 0; r < 4; ++r)
                tsum[r] += __shfl_xor(tsum[r], mask, 64);
#pragma unroll
        for (int r = 0; r < 4; ++r)
            lrow[r] = lrow[r] * alpha[r] + tsum[r];
#pragma unroll
        for (int n = 0; n < 8; ++n)
#pragma unroll
            for (int r = 0; r < 4; ++r)
                o[n][r] = o[n][r] * alpha[r];

#pragma unroll
        for (int t = 0; t < 4; ++t)
#pragma unroll
            for (int r = 0; r < 4; ++r)
                myP[(kg * 4 + r) * PSTR + t * 16 + r16] = f2b(p[t][r]);
        asm volatile("s_waitcnt lgkmcnt(0)" ::: "memory");

#pragma unroll
        for (int kc = 0; kc < 2; ++kc) {
            bf16x8 pa = *(const bf16x8*)(myP + r16 * PSTR + kc * 32 + kg * 8);
#pragma unroll
            for (int n = 0; n < 8; ++n) {
                bf16x8 vb = *(const bf16x8*)(Vt + (n * 16 + r16) * VSTR + kc * 32 + kg * 8);
                o[n] = __builtin_amdgcn_mfma_f32_16x16x32_bf16(pa, vb, o[n], 0, 0, 0);
            }
        }
        __syncthreads();
    }

#pragma unroll
    for (int n = 0; n < 8; ++n)
#pragma unroll
        for (int r = 0; r < 4; ++r) {
            int q = qbase + kg * 4 + r;
            aout[(size_t)q * HID + h * HDIM + n * 16 + r16] = f2b(o[n][r] / lrow[r]);
        }
}

extern "C" void kernel_launch(void* const* d_in, const int* in_sizes, int n_in,
                              void* d_out, int out_size, void* d_ws, size_t ws_size,
                              hipStream_t stream) {
    const float* hidden = (const float*)d_in[0];
    const float* cos_t = (const float*)d_in[2];
    const float* sin_t = (const float*)d_in[3];
    const float* q_w = (const float*)d_in[4];
    const float* q_b = (const float*)d_in[5];
    const float* k_w = (const float*)d_in[6];
    const float* k_b = (const float*)d_in[7];
    const float* v_w = (const float*)d_in[8];
    const float* v_b = (const float*)d_in[9];
    const float* o_w = (const float*)d_in[10];
    const float* o_b = (const float*)d_in[11];

    char* ws = (char*)d_ws;
    unsigned short* hbf  = (unsigned short*)ws;                   // 2048*4608 bf16
    unsigned short* attn = hbf;                                   // alias: reused after QKV GEMM
    unsigned short* wqkv = (unsigned short*)(ws + 18874368);      // 5632*4608 bf16 (dead after QKV GEMM)
    unsigned short* vtg  = wqkv;                                  // alias: V^T [4][128][2048]
    unsigned short* wo   = (unsigned short*)(ws + 70778880);      // 4608*4608 bf16
    unsigned short* qkv  = (unsigned short*)(ws + 113246208);     // 2048*5632 bf16

    dim3 blk(256);
    conv_kernel<<<2048, blk, 0, stream>>>(hidden, hbf, (SEQ * HID) / 4);
    conv_kernel<<<2048, blk, 0, stream>>>(q_w, wqkv, (HID * HID) / 4);
    conv_kernel<<<2048, blk, 0, stream>>>(k_w, wqkv + (size_t)HID * HID, (512 * HID) / 4);
    conv_kernel<<<2048, blk, 0, stream>>>(v_w, wqkv + (size_t)5120 * HID, (512 * HID) / 4);
    conv_kernel<<<2048, blk, 0, stream>>>(o_w, wo, (HID * HID) / 4);

    gemm256_kernel<<<dim3(176), dim3(512), 0, stream>>>(hbf, wqkv, qkv, q_b, k_b, v_b, NQKV, HID, 22, 0);
    rope_kernel<<<(SEQ * 40 * 64) / 256, blk, 0, stream>>>(qkv, cos_t, sin_t);
    vtrans_kernel<<<dim3(SEQ / 32, HDIM / 32, NKVH), blk, 0, stream>>>(qkv, vtg);
    attn_kernel<<<dim3(NHEAD, SEQ / 64), blk, 0, stream>>>(qkv, vtg, attn);
    gemm256_kernel<<<dim3(144), dim3(512), 0, stream>>>(attn, wo, d_out, o_b, nullptr, nullptr, HID, HID, 18, 1);
}

// Round 6
// 438.805 us; speedup vs baseline: 1.5984x; 1.0130x over previous
//
#include <hip/hip_runtime.h>
#include <stdint.h>

typedef __attribute__((ext_vector_type(8))) __bf16 bf16x8;
typedef __attribute__((ext_vector_type(4))) float f32x4;
typedef __attribute__((ext_vector_type(8))) unsigned short u16x8;
typedef __attribute__((ext_vector_type(4))) unsigned short u16x4;

#define SEQ 2048
#define HID 4608
#define NQKV 5632   // 4608 q + 512 k + 512 v
#define NHEAD 36
#define NKVH 4
#define HDIM 128
#define WINDOW 1024

__device__ __forceinline__ unsigned short f2b(float f) {
    unsigned u = __builtin_bit_cast(unsigned, f);
    u += 0x7fffu + ((u >> 16) & 1u);
    return (unsigned short)(u >> 16);
}
__device__ __forceinline__ float b2f(unsigned short h) {
    unsigned u = ((unsigned)h) << 16;
    return __builtin_bit_cast(float, u);
}

#define GLD16(gp, lp) __builtin_amdgcn_global_load_lds( \
    (const __attribute__((address_space(1))) void*)(gp), \
    (__attribute__((address_space(3))) void*)(lp), 16, 0, 0)

#define VMCNT8() asm volatile("s_waitcnt vmcnt(8)" ::: "memory")
#define VMCNT4() asm volatile("s_waitcnt vmcnt(4)" ::: "memory")
#define VMCNT0() asm volatile("s_waitcnt vmcnt(0)" ::: "memory")
// HW barrier + COMPILER memory fence (raw builtin is IntrNoMem -> loads may hoist past it)
#define BARRIER() asm volatile("s_barrier" ::: "memory")

// ---------------- f32 -> bf16 convert ----------------
__global__ __launch_bounds__(256) void conv_kernel(const float* __restrict__ src,
                                                   unsigned short* __restrict__ dst, int n4) {
    int stride = gridDim.x * blockDim.x;
    for (int i = blockIdx.x * blockDim.x + threadIdx.x; i < n4; i += stride) {
        float4 v = ((const float4*)src)[i];
        ushort4 o;
        o.x = f2b(v.x); o.y = f2b(v.y); o.z = f2b(v.z); o.w = f2b(v.w);
        ((ushort4*)dst)[i] = o;
    }
}

// ---------------- GEMM 256x256 tile, BK=64, 8 waves, true 8-phase pipeline ----------------
// C[M,N] = A[M,K] @ W[N,K]^T + bias.
// Iteration processes K-tiles (2i)->slot0, (2i+1)->slot1; stages pair i+1 in-place:
//   ph3:B0h0 ph4:A0h0 ph5:A0h1 ph6:B0h1 ph7:B1h0+B1h1 ph8:A1h0+A1h1
// waits: vmcnt(4)@ph4 (drains prev ph8 A(s1) before ph5 reads), vmcnt(8)@ph8 (drains s0).
// MFMA clusters pinned between barriers via sched_barrier(0) (rule #18: "memory"
// clobber does NOT order register-only MFMA; without pins the phases collapse).
__global__ __launch_bounds__(512, 2) void gemm256_kernel(
    const unsigned short* __restrict__ A,
    const unsigned short* __restrict__ W,
    void* __restrict__ out,
    const float* __restrict__ b0, const float* __restrict__ b1, const float* __restrict__ b2,
    int N, int K, int GX, int outf32)
{
    __shared__ alignas(16) unsigned short ldsA[2][256 * 64];
    __shared__ alignas(16) unsigned short ldsB[2][256 * 64];

    const int tid = threadIdx.x;
    const int w = tid >> 6, lane = tid & 63;
    const int r16 = lane & 15, kg = lane >> 4;
    const int wm = w >> 2, wn = w & 3;          // 2M x 4N waves

    // T1: bijective XCD swizzle (grids here are multiples of 8)
    const int cpx = gridDim.x >> 3;
    const int o = blockIdx.x;
    const int id = (o & 7) * cpx + (o >> 3);
    const int bx = id % GX, by = id / GX;
    const int row0 = by * 256, col0 = bx * 256;

    // staging geometry: half-tile = 128 rows x 64 k of one matrix; 2 gloads/thread/half
    const int lr = lane >> 3;          // row within 8-row group
    const int lc = lane & 7;           // physical 16B chunk slot
    const int cg = lc ^ lr;            // pre-swizzled global chunk (rule #21)
    const unsigned short* Abase = A + (size_t)row0 * K;
    const unsigned short* Wbase = W + (size_t)col0 * K;

    auto STG = [&](const unsigned short* Mat, unsigned short* ldsSlot, int hf, int kb) {
#pragma unroll
        for (int j = 0; j < 2; ++j) {
            int row = hf * 128 + (w * 2 + j) * 8 + lr;
            GLD16(Mat + (size_t)row * K + kb + cg * 8,
                  (char*)ldsSlot + hf * 16384 + (w * 2 + j) * 1024);
        }
    };

    const int NITER = K >> 7;          // pairs of 64-wide K-tiles
    f32x4 acc[8][4] = {};
    const int swz = r16 & 7;

    bf16x8 af[4][2], bfA[2][2], bfB[2][2];

#define DSR_A(mh, Sl) \
_Pragma("unroll") for (int mi = 0; mi < 4; ++mi) \
_Pragma("unroll") for (int kh = 0; kh < 2; ++kh) \
    af[mi][kh] = *(const bf16x8*)((Sl) + (wm * 128 + (mh) * 64 + mi * 16 + r16) * 64 + ((kh * 4 + kg) ^ swz) * 8);
#define DSR_B(nh, Sl, BF) \
_Pragma("unroll") for (int ni = 0; ni < 2; ++ni) \
_Pragma("unroll") for (int kh = 0; kh < 2; ++kh) \
    BF[ni][kh] = *(const bf16x8*)((Sl) + (wn * 64 + (nh) * 32 + ni * 16 + r16) * 64 + ((kh * 4 + kg) ^ swz) * 8);
#define MFMA_Q(mh, nh, BF) \
    asm volatile("s_waitcnt lgkmcnt(0)" ::: "memory"); \
    __builtin_amdgcn_sched_barrier(0); \
    __builtin_amdgcn_s_setprio(1); \
_Pragma("unroll") for (int mi = 0; mi < 4; ++mi) \
_Pragma("unroll") for (int ni = 0; ni < 2; ++ni) \
_Pragma("unroll") for (int kh = 0; kh < 2; ++kh) \
    acc[(mh) * 4 + mi][(nh) * 2 + ni] = __builtin_amdgcn_mfma_f32_16x16x32_bf16(af[mi][kh], BF[ni][kh], acc[(mh) * 4 + mi][(nh) * 2 + ni], 0, 0, 0); \
    __builtin_amdgcn_s_setprio(0); \
    __builtin_amdgcn_sched_barrier(0);

    // prologue: stage pair 0 fully (16 loads/thread), drain, barrier
    STG(Abase, ldsA[0], 0, 0);  STG(Abase, ldsA[0], 1, 0);
    STG(Wbase, ldsB[0], 0, 0);  STG(Wbase, ldsB[0], 1, 0);
    STG(Abase, ldsA[1], 0, 64); STG(Abase, ldsA[1], 1, 64);
    STG(Wbase, ldsB[1], 0, 64); STG(Wbase, ldsB[1], 1, 64);
    VMCNT0();
    BARRIER();

    for (int i = 0; i < NITER; ++i) {
        const unsigned short* A0 = ldsA[0];
        const unsigned short* B0 = ldsB[0];
        const unsigned short* A1 = ldsA[1];
        const unsigned short* B1 = ldsB[1];
        const bool st = (i + 1 < NITER);
        const int kb0 = (i + 1) * 128;       // next pair, slot0 tile
        const int kb1 = kb0 + 64;            // next pair, slot1 tile

        // ---- phase 1: dsr afh0(t0)+bfnh0(t0); mfma q(0,0) t0
        DSR_A(0, A0); DSR_B(0, B0, bfA);
        BARRIER();
        MFMA_Q(0, 0, bfA);
        BARRIER();
        // ---- phase 2: dsr bfnh1(t0); mfma q(0,1) t0
        DSR_B(1, B0, bfB);
        BARRIER();
        MFMA_Q(0, 1, bfB);
        BARRIER();
        // ---- phase 3: dsr afh1(t0); stage B0h0'; mfma q(1,1) t0
        DSR_A(1, A0);
        if (st) STG(Wbase, ldsB[0], 0, kb0);
        BARRIER();
        MFMA_Q(1, 1, bfB);
        BARRIER();
        // ---- phase 4: stage A0h0'; vmcnt; mfma q(1,0) t0
        if (st) { STG(Abase, ldsA[0], 0, kb0); VMCNT4(); } else { VMCNT0(); }
        BARRIER();
        MFMA_Q(1, 0, bfA);
        BARRIER();
        // ---- phase 5: dsr afh0(t1)+bfnh0(t1); stage A0h1'; mfma q(0,0) t1
        DSR_A(0, A1); DSR_B(0, B1, bfA);
        if (st) STG(Abase, ldsA[0], 1, kb0);
        BARRIER();
        MFMA_Q(0, 0, bfA);
        BARRIER();
        // ---- phase 6: dsr bfnh1(t1); stage B0h1'; mfma q(0,1) t1
        DSR_B(1, B1, bfB);
        if (st) STG(Wbase, ldsB[0], 1, kb0);
        BARRIER();
        MFMA_Q(0, 1, bfB);
        BARRIER();
        // ---- phase 7: dsr afh1(t1); stage B1h0'+B1h1'; mfma q(1,1) t1
        DSR_A(1, A1);
        if (st) { STG(Wbase, ldsB[1], 0, kb1); STG(Wbase, ldsB[1], 1, kb1); }
        BARRIER();
        MFMA_Q(1, 1, bfB);
        BARRIER();
        // ---- phase 8: stage A1h0'+A1h1'; vmcnt(8); mfma q(1,0) t1
        if (st) { STG(Abase, ldsA[1], 0, kb1); STG(Abase, ldsA[1], 1, kb1); VMCNT8(); }
        BARRIER();
        MFMA_Q(1, 0, bfA);
        BARRIER();
    }

    if (!outf32) {
        unsigned short* O = (unsigned short*)out;
#pragma unroll
        for (int m = 0; m < 8; ++m)
#pragma unroll
            for (int n = 0; n < 4; ++n)
#pragma unroll
                for (int r = 0; r < 4; ++r) {
                    int row = row0 + wm * 128 + m * 16 + kg * 4 + r;
                    int col = col0 + wn * 64 + n * 16 + r16;
                    float bias = (col < HID) ? b0[col]
                               : (col < HID + 512 ? b1[col - HID] : b2[col - HID - 512]);
                    O[(size_t)row * N + col] = f2b(acc[m][n][r] + bias);
                }
    } else {
        float* O = (float*)out;
#pragma unroll
        for (int m = 0; m < 8; ++m)
#pragma unroll
            for (int n = 0; n < 4; ++n)
#pragma unroll
                for (int r = 0; r < 4; ++r) {
                    int row = row0 + wm * 128 + m * 16 + kg * 4 + r;
                    int col = col0 + wn * 64 + n * 16 + r16;
                    O[(size_t)row * N + col] = acc[m][n][r] + b0[col];
                }
    }
#undef DSR_A
#undef DSR_B
#undef MFMA_Q
}

// ---------------- RoPE in-place on q (heads 0..35) and k (36..39) ----------------
__global__ __launch_bounds__(256) void rope_kernel(unsigned short* __restrict__ qkv,
                                                   const float* __restrict__ cos_t,
                                                   const float* __restrict__ sin_t) {
    int idx = blockIdx.x * 256 + threadIdx.x;
    int d = idx & 63;
    int t = idx >> 6;
    int head = t % 40;
    int s = t / 40;
    int base = head < NHEAD ? head * HDIM : HID + (head - NHEAD) * HDIM;
    size_t off = (size_t)s * NQKV + base;
    float x = b2f(qkv[off + d]);
    float y = b2f(qkv[off + d + 64]);
    float c = cos_t[s * HDIM + d];
    float sn = sin_t[s * HDIM + d];
    qkv[off + d]      = f2b(x * c - y * sn);
    qkv[off + d + 64] = f2b(y * c + x * sn);
}

// ---------------- V transpose: qkv V block -> vtg[kvh][128][2048] ----------------
__global__ __launch_bounds__(256) void vtrans_kernel(const unsigned short* __restrict__ qkv,
                                                     unsigned short* __restrict__ vtg) {
    __shared__ unsigned short tile[32][36];
    const int s0 = blockIdx.x * 32, d0 = blockIdx.y * 32, kvh = blockIdx.z;
    const int lid = threadIdx.x;
    {
        int sl = lid >> 3, dc = (lid & 7) * 4;
        u16x4 v = *(const u16x4*)(qkv + (size_t)(s0 + sl) * NQKV + HID + 512 + kvh * HDIM + d0 + dc);
#pragma unroll
        for (int i = 0; i < 4; ++i) tile[sl][dc + i] = v[i];
    }
    __syncthreads();
    {
        int dl = lid >> 3, sc = (lid & 7) * 4;
        u16x4 v;
#pragma unroll
        for (int i = 0; i < 4; ++i) v[i] = tile[sc + i][dl];
        *(u16x4*)(vtg + (size_t)kvh * HDIM * SEQ + (size_t)(d0 + dl) * SEQ + s0 + sc) = v;
    }
}

// ---------------- flash attention, GQA + causal + sliding window ----------------
#define KSTR 136   // Ks row stride (u16): 272B = 68 dw ≡ 4 mod 32 -> 2-way free
#define VSTR 72    // Vt row stride (u16): 144B = 36 dw ≡ 4 mod 32 -> 2-way free
#define PSTR 88
__global__ __launch_bounds__(256) void attn_kernel(const unsigned short* __restrict__ qkv,
                                                   const unsigned short* __restrict__ vtg,
                                                   unsigned short* __restrict__ aout)
{
    __shared__ alignas(16) unsigned short Ks[64 * KSTR];
    __shared__ alignas(16) unsigned short Vt[128 * VSTR];
    __shared__ alignas(16) unsigned short Ps[4 * 16 * PSTR];
    const int h = blockIdx.x, qb = blockIdx.y;
    const int q0 = qb * 64;
    const int kvh = h / 9;
    const int tid = threadIdx.x, wid = tid >> 6, lane = tid & 63;
    const int r16 = lane & 15, kg = lane >> 4;
    const int qbase = q0 + wid * 16;
    const unsigned short* vsrc = vtg + (size_t)kvh * HDIM * SEQ;

    bf16x8 qf[4];
    {
        const unsigned short* qrow = qkv + (size_t)(qbase + r16) * NQKV + h * HDIM;
#pragma unroll
        for (int kk = 0; kk < 4; ++kk)
            qf[kk] = *(const bf16x8*)(qrow + kk * 32 + kg * 8);
    }

    f32x4 o[8] = {};
    float mrow[4], lrow[4];
#pragma unroll
    for (int r = 0; r < 4; ++r) { mrow[r] = -1e30f; lrow[r] = 0.f; }

    int lo = q0 - (WINDOW - 1); if (lo < 0) lo = 0; lo &= ~63;
    unsigned short* myP = Ps + wid * 16 * PSTR;
    const float scale = 0.08838834764831845f;

    for (int kt = lo; kt <= q0; kt += 64) {
        for (int c = tid; c < 1024; c += 256) {
            int key = c >> 4, dc = c & 15;
            const unsigned short* kp = qkv + (size_t)(kt + key) * NQKV + HID + kvh * HDIM + dc * 8;
            *(u16x8*)(Ks + key * KSTR + dc * 8) = *(const u16x8*)kp;
            int d = c >> 3, k8 = (c & 7) * 8;
            *(u16x8*)(Vt + d * VSTR + k8) = *(const u16x8*)(vsrc + (size_t)d * SEQ + kt + k8);
        }
        __syncthreads();

        f32x4 sc[4] = {};
#pragma unroll
        for (int t = 0; t < 4; ++t)
#pragma unroll
            for (int kk = 0; kk < 4; ++kk) {
                bf16x8 kf = *(const bf16x8*)(Ks + (t * 16 + r16) * KSTR + kk * 32 + kg * 8);
                sc[t] = __builtin_amdgcn_mfma_f32_16x16x32_bf16(qf[kk], kf, sc[t], 0, 0, 0);
            }

        float p[4][4], mt[4];
#pragma unroll
        for (int r = 0; r < 4; ++r) mt[r] = -1e30f;
#pragma unroll
        for (int t = 0; t < 4; ++t)
#pragma unroll
            for (int r = 0; r < 4; ++r) {
                int q = qbase + kg * 4 + r;
                int key = kt + t * 16 + r16;
                bool valid = (key <= q) && (q - key < WINDOW);
                float v = valid ? sc[t][r] * scale : -1e30f;
                p[t][r] = v;
                mt[r] = fmaxf(mt[r], v);
            }
#pragma unroll
        for (int mask = 1; mask <= 8; mask <<= 1)
#pragma unroll
            for (int r = 0; r < 4; ++r)
                mt[r] = fmaxf(mt[r], __shfl_xor(mt[r], mask, 64));

        float alpha[4], tsum[4];
#pragma unroll
        for (int r = 0; r < 4; ++r) {
            float mnew = fmaxf(mrow[r], mt[r]);
            alpha[r] = __expf(mrow[r] - mnew);
            mrow[r] = mnew;
            tsum[r] = 0.f;
        }
#pragma unroll
        for (int t = 0; t < 4; ++t)
#pragma unroll
            for (int r = 0; r < 4; ++r) {
                float e = __expf(p[t][r] - mrow[r]);
                p[t][r] = e;
                tsum[r] += e;
            }
#pragma unroll
        for (int mask = 1; mask <= 8; mask <<= 1)
#pragma unroll
            for (int r = 0; r < 4; ++r)
                tsum[r] += __shfl_xor(tsum[r], mask, 64);
#pragma unroll
        for (int r = 0; r < 4; ++r)
            lrow[r] = lrow[r] * alpha[r] + tsum[r];
#pragma unroll
        for (int n = 0; n < 8; ++n)
#pragma unroll
            for (int r = 0; r < 4; ++r)
                o[n][r] = o[n][r] * alpha[r];

#pragma unroll
        for (int t = 0; t < 4; ++t)
#pragma unroll
            for (int r = 0; r < 4; ++r)
                myP[(kg * 4 + r) * PSTR + t * 16 + r16] = f2b(p[t][r]);
        asm volatile("s_waitcnt lgkmcnt(0)" ::: "memory");

#pragma unroll
        for (int kc = 0; kc < 2; ++kc) {
            bf16x8 pa = *(const bf16x8*)(myP + r16 * PSTR + kc * 32 + kg * 8);
#pragma unroll
            for (int n = 0; n < 8; ++n) {
                bf16x8 vb = *(const bf16x8*)(Vt + (n * 16 + r16) * VSTR + kc * 32 + kg * 8);
                o[n] = __builtin_amdgcn_mfma_f32_16x16x32_bf16(pa, vb, o[n], 0, 0, 0);
            }
        }
        __syncthreads();
    }

#pragma unroll
    for (int n = 0; n < 8; ++n)
#pragma unroll
        for (int r = 0; r < 4; ++r) {
            int q = qbase + kg * 4 + r;
            aout[(size_t)q * HID + h * HDIM + n * 16 + r16] = f2b(o[n][r] / lrow[r]);
        }
}

extern "C" void kernel_launch(void* const* d_in, const int* in_sizes, int n_in,
                              void* d_out, int out_size, void* d_ws, size_t ws_size,
                              hipStream_t stream) {
    const float* hidden = (const float*)d_in[0];
    const float* cos_t = (const float*)d_in[2];
    const float* sin_t = (const float*)d_in[3];
    const float* q_w = (const float*)d_in[4];
    const float* q_b = (const float*)d_in[5];
    const float* k_w = (const float*)d_in[6];
    const float* k_b = (const float*)d_in[7];
    const float* v_w = (const float*)d_in[8];
    const float* v_b = (const float*)d_in[9];
    const float* o_w = (const float*)d_in[10];
    const float* o_b = (const float*)d_in[11];

    char* ws = (char*)d_ws;
    unsigned short* hbf  = (unsigned short*)ws;                   // 2048*4608 bf16
    unsigned short* attn = hbf;                                   // alias: reused after QKV GEMM
    unsigned short* wqkv = (unsigned short*)(ws + 18874368);      // 5632*4608 bf16 (dead after QKV GEMM)
    unsigned short* vtg  = wqkv;                                  // alias: V^T [4][128][2048]
    unsigned short* wo   = (unsigned short*)(ws + 70778880);      // 4608*4608 bf16
    unsigned short* qkv  = (unsigned short*)(ws + 113246208);     // 2048*5632 bf16

    dim3 blk(256);
    conv_kernel<<<2048, blk, 0, stream>>>(hidden, hbf, (SEQ * HID) / 4);
    conv_kernel<<<2048, blk, 0, stream>>>(q_w, wqkv, (HID * HID) / 4);
    conv_kernel<<<2048, blk, 0, stream>>>(k_w, wqkv + (size_t)HID * HID, (512 * HID) / 4);
    conv_kernel<<<2048, blk, 0, stream>>>(v_w, wqkv + (size_t)5120 * HID, (512 * HID) / 4);
    conv_kernel<<<2048, blk, 0, stream>>>(o_w, wo, (HID * HID) / 4);

    gemm256_kernel<<<dim3(176), dim3(512), 0, stream>>>(hbf, wqkv, qkv, q_b, k_b, v_b, NQKV, HID, 22, 0);
    rope_kernel<<<(SEQ * 40 * 64) / 256, blk, 0, stream>>>(qkv, cos_t, sin_t);
    vtrans_kernel<<<dim3(SEQ / 32, HDIM / 32, NKVH), blk, 0, stream>>>(qkv, vtg);
    attn_kernel<<<dim3(NHEAD, SEQ / 64), blk, 0, stream>>>(qkv, vtg, attn);
    gemm256_kernel<<<dim3(144), dim3(512), 0, stream>>>(attn, wo, d_out, o_b, nullptr, nullptr, HID, HID, 18, 1);
}

// Round 8
// 433.001 us; speedup vs baseline: 1.6198x; 1.0134x over previous
//
#include <hip/hip_runtime.h>
#include <stdint.h>

typedef __attribute__((ext_vector_type(8))) __bf16 bf16x8;
typedef __attribute__((ext_vector_type(4))) float f32x4;
typedef __attribute__((ext_vector_type(8))) unsigned short u16x8;
typedef __attribute__((ext_vector_type(4))) unsigned short u16x4;

#define SEQ 2048
#define HID 4608
#define NQKV 5632   // 4608 q + 512 k + 512 v
#define NHEAD 36
#define NKVH 4
#define HDIM 128
#define WINDOW 1024

__device__ __forceinline__ unsigned short f2b(float f) {
    unsigned u = __builtin_bit_cast(unsigned, f);
    u += 0x7fffu + ((u >> 16) & 1u);
    return (unsigned short)(u >> 16);
}
__device__ __forceinline__ float b2f(unsigned short h) {
    unsigned u = ((unsigned)h) << 16;
    return __builtin_bit_cast(float, u);
}

#define GLD16(gp, lp) __builtin_amdgcn_global_load_lds( \
    (const __attribute__((address_space(1))) void*)(gp), \
    (__attribute__((address_space(3))) void*)(lp), 16, 0, 0)

#define VMCNT8() asm volatile("s_waitcnt vmcnt(8)" ::: "memory")
#define VMCNT4() asm volatile("s_waitcnt vmcnt(4)" ::: "memory")
#define VMCNT0() asm volatile("s_waitcnt vmcnt(0)" ::: "memory")
// HW barrier + COMPILER memory fence (raw builtin is IntrNoMem -> loads may hoist past it)
#define BARRIER() asm volatile("s_barrier" ::: "memory")

// ---------------- merged f32 -> bf16 convert (5 segments, one launch) ----------------
__global__ __launch_bounds__(256) void conv_all_kernel(
    const float* __restrict__ s0, unsigned short* __restrict__ d0, int n0,
    const float* __restrict__ s1, unsigned short* __restrict__ d1, int n1,
    const float* __restrict__ s2, unsigned short* __restrict__ d2, int n2,
    const float* __restrict__ s3, unsigned short* __restrict__ d3, int n3,
    const float* __restrict__ s4, unsigned short* __restrict__ d4, int n4)
{
    int total = n0 + n1 + n2 + n3 + n4;
    int stride = gridDim.x * blockDim.x;
    for (int i = blockIdx.x * blockDim.x + threadIdx.x; i < total; i += stride) {
        const float* src; unsigned short* dst; int j = i;
        if (j < n0) { src = s0; dst = d0; }
        else if ((j -= n0) < n1) { src = s1; dst = d1; }
        else if ((j -= n1) < n2) { src = s2; dst = d2; }
        else if ((j -= n2) < n3) { src = s3; dst = d3; }
        else { j -= n3; src = s4; dst = d4; }
        float4 v = ((const float4*)src)[j];
        ushort4 o;
        o.x = f2b(v.x); o.y = f2b(v.y); o.z = f2b(v.z); o.w = f2b(v.w);
        ((ushort4*)dst)[j] = o;
    }
}

// ---------------- GEMM 256x256, BK=64, 8 waves, 8-phase (R6-proven schedule) ----------------
// Iteration processes K-tiles (2i)->slot0, (2i+1)->slot1; stages pair i+1 in-place:
//   ph3:B0h0 ph4:A0h0 ph5:A0h1 ph6:B0h1 ph7:B1h0+B1h1 ph8:A1h0+A1h1
// waits: vmcnt(4)@ph4 (drains prev ph8 A(s1) before ph5 reads), vmcnt(8)@ph8 (drains s0).
// Every DSR completes before its phase's trailing barrier (lgkmcnt inside MFMA_Q +
// barrier) -> next-phase staging can never overwrite rows still being read.
__global__ __launch_bounds__(512, 2) void gemm256_kernel(
    const unsigned short* __restrict__ A,
    const unsigned short* __restrict__ W,
    void* __restrict__ out,
    const float* __restrict__ b0, const float* __restrict__ b1, const float* __restrict__ b2,
    int N, int K, int GX, int outf32)
{
    __shared__ alignas(16) unsigned short ldsA[2][256 * 64];
    __shared__ alignas(16) unsigned short ldsB[2][256 * 64];

    const int tid = threadIdx.x;
    const int w = tid >> 6, lane = tid & 63;
    const int r16 = lane & 15, kg = lane >> 4;
    const int wm = w >> 2, wn = w & 3;          // 2M x 4N waves

    const int cpx = gridDim.x >> 3;
    const int o = blockIdx.x;
    const int id = (o & 7) * cpx + (o >> 3);
    const int bx = id % GX, by = id / GX;
    const int row0 = by * 256, col0 = bx * 256;

    const int lr = lane >> 3;
    const int lc = lane & 7;
    const int cg = lc ^ lr;            // pre-swizzled global chunk (rule #21)
    const unsigned short* Abase = A + (size_t)row0 * K;
    const unsigned short* Wbase = W + (size_t)col0 * K;

    auto STG = [&](const unsigned short* Mat, unsigned short* ldsSlot, int hf, int kb) {
#pragma unroll
        for (int j = 0; j < 2; ++j) {
            int row = hf * 128 + (w * 2 + j) * 8 + lr;
            GLD16(Mat + (size_t)row * K + kb + cg * 8,
                  (char*)ldsSlot + hf * 16384 + (w * 2 + j) * 1024);
        }
    };

    const int NITER = K >> 7;          // pairs of 64-wide K-tiles
    f32x4 acc[8][4] = {};
    const int swz = r16 & 7;

    bf16x8 af[4][2], bfA[2][2], bfB[2][2];

#define DSR_A(mh, Sl) \
_Pragma("unroll") for (int mi = 0; mi < 4; ++mi) \
_Pragma("unroll") for (int kh = 0; kh < 2; ++kh) \
    af[mi][kh] = *(const bf16x8*)((Sl) + (wm * 128 + (mh) * 64 + mi * 16 + r16) * 64 + ((kh * 4 + kg) ^ swz) * 8);
#define DSR_B(nh, Sl, BF) \
_Pragma("unroll") for (int ni = 0; ni < 2; ++ni) \
_Pragma("unroll") for (int kh = 0; kh < 2; ++kh) \
    BF[ni][kh] = *(const bf16x8*)((Sl) + (wn * 64 + (nh) * 32 + ni * 16 + r16) * 64 + ((kh * 4 + kg) ^ swz) * 8);
#define MFMA_Q(mh, nh, BF) \
    asm volatile("s_waitcnt lgkmcnt(0)" ::: "memory"); \
    __builtin_amdgcn_sched_barrier(0); \
    __builtin_amdgcn_s_setprio(1); \
_Pragma("unroll") for (int mi = 0; mi < 4; ++mi) \
_Pragma("unroll") for (int ni = 0; ni < 2; ++ni) \
_Pragma("unroll") for (int kh = 0; kh < 2; ++kh) \
    acc[(mh) * 4 + mi][(nh) * 2 + ni] = __builtin_amdgcn_mfma_f32_16x16x32_bf16(af[mi][kh], BF[ni][kh], acc[(mh) * 4 + mi][(nh) * 2 + ni], 0, 0, 0); \
    __builtin_amdgcn_s_setprio(0); \
    __builtin_amdgcn_sched_barrier(0);

    // prologue: stage pair 0 fully (16 loads/thread), drain, barrier
    STG(Abase, ldsA[0], 0, 0);  STG(Abase, ldsA[0], 1, 0);
    STG(Wbase, ldsB[0], 0, 0);  STG(Wbase, ldsB[0], 1, 0);
    STG(Abase, ldsA[1], 0, 64); STG(Abase, ldsA[1], 1, 64);
    STG(Wbase, ldsB[1], 0, 64); STG(Wbase, ldsB[1], 1, 64);
    VMCNT0();
    BARRIER();

    for (int i = 0; i < NITER; ++i) {
        const unsigned short* A0 = ldsA[0];
        const unsigned short* B0 = ldsB[0];
        const unsigned short* A1 = ldsA[1];
        const unsigned short* B1 = ldsB[1];
        const bool st = (i + 1 < NITER);
        const int kb0 = (i + 1) * 128;       // next pair, slot0 tile
        const int kb1 = kb0 + 64;            // next pair, slot1 tile

        // ---- phase 1: dsr afh0(t0)+bfnh0(t0); mfma q(0,0) t0
        DSR_A(0, A0); DSR_B(0, B0, bfA);
        BARRIER();
        MFMA_Q(0, 0, bfA);
        BARRIER();
        // ---- phase 2: dsr bfnh1(t0); mfma q(0,1) t0
        DSR_B(1, B0, bfB);
        BARRIER();
        MFMA_Q(0, 1, bfB);
        BARRIER();
        // ---- phase 3: dsr afh1(t0); stage B0h0'; mfma q(1,1) t0
        DSR_A(1, A0);
        if (st) STG(Wbase, ldsB[0], 0, kb0);
        BARRIER();
        MFMA_Q(1, 1, bfB);
        BARRIER();
        // ---- phase 4: stage A0h0'; vmcnt; mfma q(1,0) t0
        if (st) { STG(Abase, ldsA[0], 0, kb0); VMCNT4(); } else { VMCNT0(); }
        BARRIER();
        MFMA_Q(1, 0, bfA);
        BARRIER();
        // ---- phase 5: dsr afh0(t1)+bfnh0(t1); stage A0h1'; mfma q(0,0) t1
        DSR_A(0, A1); DSR_B(0, B1, bfA);
        if (st) STG(Abase, ldsA[0], 1, kb0);
        BARRIER();
        MFMA_Q(0, 0, bfA);
        BARRIER();
        // ---- phase 6: dsr bfnh1(t1); stage B0h1'; mfma q(0,1) t1
        DSR_B(1, B1, bfB);
        if (st) STG(Wbase, ldsB[0], 1, kb0);
        BARRIER();
        MFMA_Q(0, 1, bfB);
        BARRIER();
        // ---- phase 7: dsr afh1(t1); stage B1h0'+B1h1'; mfma q(1,1) t1
        DSR_A(1, A1);
        if (st) { STG(Wbase, ldsB[1], 0, kb1); STG(Wbase, ldsB[1], 1, kb1); }
        BARRIER();
        MFMA_Q(1, 1, bfB);
        BARRIER();
        // ---- phase 8: stage A1h0'+A1h1'; vmcnt(8); mfma q(1,0) t1
        if (st) { STG(Abase, ldsA[1], 0, kb1); STG(Abase, ldsA[1], 1, kb1); VMCNT8(); }
        BARRIER();
        MFMA_Q(1, 0, bfA);
        BARRIER();
    }

    if (!outf32) {
        unsigned short* O = (unsigned short*)out;
#pragma unroll
        for (int m = 0; m < 8; ++m)
#pragma unroll
            for (int n = 0; n < 4; ++n)
#pragma unroll
                for (int r = 0; r < 4; ++r) {
                    int row = row0 + wm * 128 + m * 16 + kg * 4 + r;
                    int col = col0 + wn * 64 + n * 16 + r16;
                    float bias = (col < HID) ? b0[col]
                               : (col < HID + 512 ? b1[col - HID] : b2[col - HID - 512]);
                    O[(size_t)row * N + col] = f2b(acc[m][n][r] + bias);
                }
    } else {
        float* O = (float*)out;
#pragma unroll
        for (int m = 0; m < 8; ++m)
#pragma unroll
            for (int n = 0; n < 4; ++n)
#pragma unroll
                for (int r = 0; r < 4; ++r) {
                    int row = row0 + wm * 128 + m * 16 + kg * 4 + r;
                    int col = col0 + wn * 64 + n * 16 + r16;
                    O[(size_t)row * N + col] = acc[m][n][r] + b0[col];
                }
    }
#undef DSR_A
#undef DSR_B
#undef MFMA_Q
}

// ---------------- RoPE in-place on q (heads 0..35) and k (36..39) ----------------
__global__ __launch_bounds__(256) void rope_kernel(unsigned short* __restrict__ qkv,
                                                   const float* __restrict__ cos_t,
                                                   const float* __restrict__ sin_t) {
    int idx = blockIdx.x * 256 + threadIdx.x;
    int d = idx & 63;
    int t = idx >> 6;
    int head = t % 40;
    int s = t / 40;
    int base = head < NHEAD ? head * HDIM : HID + (head - NHEAD) * HDIM;
    size_t off = (size_t)s * NQKV + base;
    float x = b2f(qkv[off + d]);
    float y = b2f(qkv[off + d + 64]);
    float c = cos_t[s * HDIM + d];
    float sn = sin_t[s * HDIM + d];
    qkv[off + d]      = f2b(x * c - y * sn);
    qkv[off + d + 64] = f2b(y * c + x * sn);
}

// ---------------- V transpose: qkv V block -> vtg[kvh][128][2048] ----------------
__global__ __launch_bounds__(256) void vtrans_kernel(const unsigned short* __restrict__ qkv,
                                                     unsigned short* __restrict__ vtg) {
    __shared__ unsigned short tile[32][36];
    const int s0 = blockIdx.x * 32, d0 = blockIdx.y * 32, kvh = blockIdx.z;
    const int lid = threadIdx.x;
    {
        int sl = lid >> 3, dc = (lid & 7) * 4;
        u16x4 v = *(const u16x4*)(qkv + (size_t)(s0 + sl) * NQKV + HID + 512 + kvh * HDIM + d0 + dc);
#pragma unroll
        for (int i = 0; i < 4; ++i) tile[sl][dc + i] = v[i];
    }
    __syncthreads();
    {
        int dl = lid >> 3, sc = (lid & 7) * 4;
        u16x4 v;
#pragma unroll
        for (int i = 0; i < 4; ++i) v[i] = tile[sc + i][dl];
        *(u16x4*)(vtg + (size_t)kvh * HDIM * SEQ + (size_t)(d0 + dl) * SEQ + s0 + sc) = v;
    }
}

// ---------------- flash attention, GQA + causal + sliding window ----------------
// T14 async-stage: next KV tile prefetched into registers right after the staging
// barrier (hidden under QK/softmax/PV); ds_write from regs at loop head. The
// end-of-iter barrier is a raw s_barrier (no vmcnt drain) so prefetch stays in
// flight; the dependent ds_write forces the compiler's vmcnt wait next iter.
#define KSTR 136   // Ks row stride (u16): 272B = 68 dw ≡ 4 mod 32 -> 2-way free
#define VSTR 72    // Vt row stride (u16): 144B = 36 dw ≡ 4 mod 32 -> 2-way free
#define PSTR 88
__global__ __launch_bounds__(256) void attn_kernel(const unsigned short* __restrict__ qkv,
                                                   const unsigned short* __restrict__ vtg,
                                                   unsigned short* __restrict__ aout)
{
    __shared__ alignas(16) unsigned short Ks[64 * KSTR];
    __shared__ alignas(16) unsigned short Vt[128 * VSTR];
    __shared__ alignas(16) unsigned short Ps[4 * 16 * PSTR];
    const int h = blockIdx.x, qb = blockIdx.y;
    const int q0 = qb * 64;
    const int kvh = h / 9;
    const int tid = threadIdx.x, wid = tid >> 6, lane = tid & 63;
    const int r16 = lane & 15, kg = lane >> 4;
    const int qbase = q0 + wid * 16;
    const unsigned short* vsrc = vtg + (size_t)kvh * HDIM * SEQ;

    bf16x8 qf[4];
    {
        const unsigned short* qrow = qkv + (size_t)(qbase + r16) * NQKV + h * HDIM;
#pragma unroll
        for (int kk = 0; kk < 4; ++kk)
            qf[kk] = *(const bf16x8*)(qrow + kk * 32 + kg * 8);
    }

    f32x4 o[8] = {};
    float mrow[4], lrow[4];
#pragma unroll
    for (int r = 0; r < 4; ++r) { mrow[r] = -1e30f; lrow[r] = 0.f; }

    int lo = q0 - (WINDOW - 1); if (lo < 0) lo = 0; lo &= ~63;
    unsigned short* myP = Ps + wid * 16 * PSTR;
    const float scale = 0.08838834764831845f;

    // register prefetch buffers (wave-private; static indices per rule #20)
    u16x8 kreg[4], vreg[4];
#define PREF(KT) \
_Pragma("unroll") for (int j = 0; j < 4; ++j) { \
        int c = tid + j * 256; \
        int key = c >> 4, dc = c & 15; \
        kreg[j] = *(const u16x8*)(qkv + (size_t)((KT) + key) * NQKV + HID + kvh * HDIM + dc * 8); \
        int d = c >> 3, k8 = (c & 7) * 8; \
        vreg[j] = *(const u16x8*)(vsrc + (size_t)d * SEQ + (KT) + k8); \
    }

    PREF(lo);

    for (int kt = lo; kt <= q0; kt += 64) {
        // commit staged regs to LDS
#pragma unroll
        for (int j = 0; j < 4; ++j) {
            int c = tid + j * 256;
            int key = c >> 4, dc = c & 15;
            *(u16x8*)(Ks + key * KSTR + dc * 8) = kreg[j];
            int d = c >> 3, k8 = (c & 7) * 8;
            *(u16x8*)(Vt + d * VSTR + k8) = vreg[j];
        }
        __syncthreads();                 // ds_writes visible to all waves

        if (kt + 64 <= q0) { PREF(kt + 64); }   // issue next-tile loads; hidden under compute

        f32x4 sc[4] = {};
#pragma unroll
        for (int t = 0; t < 4; ++t)
#pragma unroll
            for (int kk = 0; kk < 4; ++kk) {
                bf16x8 kf = *(const bf16x8*)(Ks + (t * 16 + r16) * KSTR + kk * 32 + kg * 8);
                sc[t] = __builtin_amdgcn_mfma_f32_16x16x32_bf16(qf[kk], kf, sc[t], 0, 0, 0);
            }

        float p[4][4], mt[4];
#pragma unroll
        for (int r = 0; r < 4; ++r) mt[r] = -1e30f;
#pragma unroll
        for (int t = 0; t < 4; ++t)
#pragma unroll
            for (int r = 0; r < 4; ++r) {
                int q = qbase + kg * 4 + r;
                int key = kt + t * 16 + r16;
                bool valid = (key <= q) && (q - key < WINDOW);
                float v = valid ? sc[t][r] * scale : -1e30f;
                p[t][r] = v;
                mt[r] = fmaxf(mt[r], v);
            }
#pragma unroll
        for (int mask = 1; mask <= 8; mask <<= 1)
#pragma unroll
            for (int r = 0; r < 4; ++r)
                mt[r] = fmaxf(mt[r], __shfl_xor(mt[r], mask, 64));

        float alpha[4], tsum[4];
#pragma unroll
        for (int r = 0; r < 4; ++r) {
            float mnew = fmaxf(mrow[r], mt[r]);
            alpha[r] = __expf(mrow[r] - mnew);
            mrow[r] = mnew;
            tsum[r] = 0.f;
        }
#pragma unroll
        for (int t = 0; t < 4; ++t)
#pragma unroll
            for (int r = 0; r < 4; ++r) {
                float e = __expf(p[t][r] - mrow[r]);
                p[t][r] = e;
                tsum[r] += e;
            }
#pragma unroll
        for (int mask = 1; mask <= 8; mask <<= 1)
#pragma unroll
            for (int r = 0; r < 4; ++r)
                tsum[r] += __shfl_xor(tsum[r], mask, 64);
#pragma unroll
        for (int r = 0; r < 4; ++r)
            lrow[r] = lrow[r] * alpha[r] + tsum[r];
#pragma unroll
        for (int n = 0; n < 8; ++n)
#pragma unroll
            for (int r = 0; r < 4; ++r)
                o[n][r] = o[n][r] * alpha[r];

#pragma unroll
        for (int t = 0; t < 4; ++t)
#pragma unroll
            for (int r = 0; r < 4; ++r)
                myP[(kg * 4 + r) * PSTR + t * 16 + r16] = f2b(p[t][r]);
        asm volatile("s_waitcnt lgkmcnt(0)" ::: "memory");

#pragma unroll
        for (int kc = 0; kc < 2; ++kc) {
            bf16x8 pa = *(const bf16x8*)(myP + r16 * PSTR + kc * 32 + kg * 8);
#pragma unroll
            for (int n = 0; n < 8; ++n) {
                bf16x8 vb = *(const bf16x8*)(Vt + (n * 16 + r16) * VSTR + kc * 32 + kg * 8);
                o[n] = __builtin_amdgcn_mfma_f32_16x16x32_bf16(pa, vb, o[n], 0, 0, 0);
            }
        }
        BARRIER();                       // no vmcnt drain: keep prefetch in flight
    }
#undef PREF

#pragma unroll
    for (int n = 0; n < 8; ++n)
#pragma unroll
        for (int r = 0; r < 4; ++r) {
            int q = qbase + kg * 4 + r;
            aout[(size_t)q * HID + h * HDIM + n * 16 + r16] = f2b(o[n][r] / lrow[r]);
        }
}

extern "C" void kernel_launch(void* const* d_in, const int* in_sizes, int n_in,
                              void* d_out, int out_size, void* d_ws, size_t ws_size,
                              hipStream_t stream) {
    const float* hidden = (const float*)d_in[0];
    const float* cos_t = (const float*)d_in[2];
    const float* sin_t = (const float*)d_in[3];
    const float* q_w = (const float*)d_in[4];
    const float* q_b = (const float*)d_in[5];
    const float* k_w = (const float*)d_in[6];
    const float* k_b = (const float*)d_in[7];
    const float* v_w = (const float*)d_in[8];
    const float* v_b = (const float*)d_in[9];
    const float* o_w = (const float*)d_in[10];
    const float* o_b = (const float*)d_in[11];

    char* ws = (char*)d_ws;
    unsigned short* hbf  = (unsigned short*)ws;                   // 2048*4608 bf16
    unsigned short* attn = hbf;                                   // alias: reused after QKV GEMM
    unsigned short* wqkv = (unsigned short*)(ws + 18874368);      // 5632*4608 bf16 (dead after QKV GEMM)
    unsigned short* vtg  = wqkv;                                  // alias: V^T [4][128][2048]
    unsigned short* wo   = (unsigned short*)(ws + 70778880);      // 4608*4608 bf16
    unsigned short* qkv  = (unsigned short*)(ws + 113246208);     // 2048*5632 bf16

    dim3 blk(256);
    conv_all_kernel<<<4096, blk, 0, stream>>>(
        hidden, hbf,                          (SEQ * HID) / 4,
        q_w,    wqkv,                         (HID * HID) / 4,
        k_w,    wqkv + (size_t)HID * HID,     (512 * HID) / 4,
        v_w,    wqkv + (size_t)5120 * HID,    (512 * HID) / 4,
        o_w,    wo,                           (HID * HID) / 4);

    gemm256_kernel<<<dim3(176), dim3(512), 0, stream>>>(hbf, wqkv, qkv, q_b, k_b, v_b, NQKV, HID, 22, 0);
    rope_kernel<<<(SEQ * 40 * 64) / 256, blk, 0, stream>>>(qkv, cos_t, sin_t);
    vtrans_kernel<<<dim3(SEQ / 32, HDIM / 32, NKVH), blk, 0, stream>>>(qkv, vtg);
    attn_kernel<<<dim3(NHEAD, SEQ / 64), blk, 0, stream>>>(qkv, vtg, attn);
    gemm256_kernel<<<dim3(144), dim3(512), 0, stream>>>(attn, wo, d_out, o_b, nullptr, nullptr, HID, HID, 18, 1);
}

// Round 9
// 422.426 us; speedup vs baseline: 1.6604x; 1.0250x over previous
//
#include <hip/hip_runtime.h>
#include <stdint.h>

typedef __attribute__((ext_vector_type(8))) __bf16 bf16x8;
typedef __attribute__((ext_vector_type(4))) float f32x4;
typedef __attribute__((ext_vector_type(8))) unsigned short u16x8;
typedef __attribute__((ext_vector_type(4))) unsigned short u16x4;

#define SEQ 2048
#define HID 4608
#define NQKV 5632   // 4608 q + 512 k + 512 v
#define NHEAD 36
#define NKVH 4
#define HDIM 128
#define WINDOW 1024

__device__ __forceinline__ unsigned short f2b(float f) {
    unsigned u = __builtin_bit_cast(unsigned, f);
    u += 0x7fffu + ((u >> 16) & 1u);
    return (unsigned short)(u >> 16);
}
__device__ __forceinline__ float b2f(unsigned short h) {
    unsigned u = ((unsigned)h) << 16;
    return __builtin_bit_cast(float, u);
}

#define GLD16(gp, lp) __builtin_amdgcn_global_load_lds( \
    (const __attribute__((address_space(1))) void*)(gp), \
    (__attribute__((address_space(3))) void*)(lp), 16, 0, 0)

#define VMCNT2() asm volatile("s_waitcnt vmcnt(2)" ::: "memory")
#define VMCNT0() asm volatile("s_waitcnt vmcnt(0)" ::: "memory")
#define LGKM0()  asm volatile("s_waitcnt lgkmcnt(0)" ::: "memory")
#define SB0()    __builtin_amdgcn_sched_barrier(0)
// HW barrier + COMPILER memory fence (raw builtin is IntrNoMem -> loads may hoist past it)
#define BARRIER() asm volatile("s_barrier" ::: "memory")

// ---------------- merged f32 -> bf16 convert (5 segments, one launch) ----------------
__global__ __launch_bounds__(256) void conv_all_kernel(
    const float* __restrict__ s0, unsigned short* __restrict__ d0, int n0,
    const float* __restrict__ s1, unsigned short* __restrict__ d1, int n1,
    const float* __restrict__ s2, unsigned short* __restrict__ d2, int n2,
    const float* __restrict__ s3, unsigned short* __restrict__ d3, int n3,
    const float* __restrict__ s4, unsigned short* __restrict__ d4, int n4)
{
    int total = n0 + n1 + n2 + n3 + n4;
    int stride = gridDim.x * blockDim.x;
    for (int i = blockIdx.x * blockDim.x + threadIdx.x; i < total; i += stride) {
        const float* src; unsigned short* dst; int j = i;
        if (j < n0) { src = s0; dst = d0; }
        else if ((j -= n0) < n1) { src = s1; dst = d1; }
        else if ((j -= n1) < n2) { src = s2; dst = d2; }
        else if ((j -= n2) < n3) { src = s3; dst = d3; }
        else { j -= n3; src = s4; dst = d4; }
        float4 v = ((const float4*)src)[j];
        ushort4 o;
        o.x = f2b(v.x); o.y = f2b(v.y); o.z = f2b(v.z); o.w = f2b(v.w);
        ((ushort4*)dst)[j] = o;
    }
}

// ---------------- GEMM 256x256, BK=64, 8 waves, pipelined 8-window schedule ----------------
// Frags for window W+1 load at W's head (hidden under W's MFMA); afX/afY double-buffer.
// DSR: W1pre bfB=B0n1 | W2pre afY=A0h1 | W3pre afX=A1h0 (vmcnt2 gate) | W4post bfA=B1n0
//      W5pre bfB=B1n1 | W6pre afY=A1h1 | W7pre afX=A0'h0 (vmcnt2 gate) | W8post bfA=B0'n0
// STG: W1 A1h1(cur) | W2 B0h0' | W3 A0h0'+B0h1' | W5 A0h1' | W6 B1h0' | W7 A1h0'+B1h1'
// Gates: vmcnt(2)@W3 retires {pW5,pW6,pW7,W1} = slot1 complete; vmcnt(2)@W7 retires
// {W2,W3,W5} = slot0' complete. All retirees >=2 windows old (HBM latency hidden).
__global__ __launch_bounds__(512, 2) void gemm256_kernel(
    const unsigned short* __restrict__ A,
    const unsigned short* __restrict__ W,
    void* __restrict__ out,
    const float* __restrict__ b0, const float* __restrict__ b1, const float* __restrict__ b2,
    int N, int K, int GX, int outf32)
{
    __shared__ alignas(16) unsigned short ldsA[2][256 * 64];
    __shared__ alignas(16) unsigned short ldsB[2][256 * 64];

    const int tid = threadIdx.x;
    const int lane = tid & 63;
    const int w  = __builtin_amdgcn_readfirstlane(tid >> 6);   // wave-uniform -> SGPR
    const int r16 = lane & 15, kg = lane >> 4;
    const int wm = w >> 2, wn = w & 3;          // 2M x 4N waves

    const int cpx = gridDim.x >> 3;
    const int o = blockIdx.x;
    const int id = (o & 7) * cpx + (o >> 3);
    const int bx = id % GX, by = id / GX;
    const int row0 = by * 256, col0 = bx * 256;

    const int lr = lane >> 3;
    const int lc = lane & 7;
    const int cg = lc ^ lr;            // pre-swizzled global chunk (rule #21)
    const unsigned short* Abase = A + (size_t)row0 * K;
    const unsigned short* Wbase = W + (size_t)col0 * K;

    auto STG = [&](const unsigned short* Mat, unsigned short* ldsSlot, int hf, int kb) {
#pragma unroll
        for (int j = 0; j < 2; ++j) {
            int row = hf * 128 + (w * 2 + j) * 8 + lr;
            GLD16(Mat + (size_t)row * K + kb + cg * 8,
                  (char*)ldsSlot + hf * 16384 + (w * 2 + j) * 1024);
        }
    };

    const int NITER = K >> 7;          // pairs of 64-wide K-tiles
    f32x4 acc[8][4] = {};
    const int swz = r16 & 7;

    bf16x8 afX[4][2], afY[4][2], bfA[2][2], bfB[2][2];

#define DSR_A(mh, Sl, AF) \
_Pragma("unroll") for (int mi = 0; mi < 4; ++mi) \
_Pragma("unroll") for (int kh = 0; kh < 2; ++kh) \
    AF[mi][kh] = *(const bf16x8*)((Sl) + (wm * 128 + (mh) * 64 + mi * 16 + r16) * 64 + ((kh * 4 + kg) ^ swz) * 8);
#define DSR_B(nh, Sl, BF) \
_Pragma("unroll") for (int ni = 0; ni < 2; ++ni) \
_Pragma("unroll") for (int kh = 0; kh < 2; ++kh) \
    BF[ni][kh] = *(const bf16x8*)((Sl) + (wn * 64 + (nh) * 32 + ni * 16 + r16) * 64 + ((kh * 4 + kg) ^ swz) * 8);
#define MFMA_Q(mh, nh, AF, BF) \
    SB0(); \
    __builtin_amdgcn_s_setprio(1); \
_Pragma("unroll") for (int mi = 0; mi < 4; ++mi) \
_Pragma("unroll") for (int ni = 0; ni < 2; ++ni) \
_Pragma("unroll") for (int kh = 0; kh < 2; ++kh) \
    acc[(mh) * 4 + mi][(nh) * 2 + ni] = __builtin_amdgcn_mfma_f32_16x16x32_bf16(AF[mi][kh], BF[ni][kh], acc[(mh) * 4 + mi][(nh) * 2 + ni], 0, 0, 0); \
    __builtin_amdgcn_s_setprio(0); \
    SB0();

    const unsigned short* A0 = ldsA[0];
    const unsigned short* B0 = ldsB[0];
    const unsigned short* A1 = ldsA[1];
    const unsigned short* B1 = ldsB[1];

    // prologue: stage 7 halves (A1h1 deferred to W1); initial frags afX=A0h0, bfA=B0n0
    STG(Abase, ldsA[0], 0, 0);  STG(Abase, ldsA[0], 1, 0);
    STG(Wbase, ldsB[0], 0, 0);  STG(Wbase, ldsB[0], 1, 0);
    STG(Abase, ldsA[1], 0, 64);
    STG(Wbase, ldsB[1], 0, 64); STG(Wbase, ldsB[1], 1, 64);
    VMCNT0();
    BARRIER();
    DSR_A(0, A0, afX); DSR_B(0, B0, bfA);

    for (int i = 0; i < NITER; ++i) {
        const bool st = (i + 1 < NITER);
        const int kbc1 = i * 128 + 64;       // current pair slot1 K-offset
        const int kb0 = (i + 1) * 128;
        const int kb1 = kb0 + 64;

        // W1: pre bfB=B0n1; mfma q00 t0; stg A1h1(cur)
        LGKM0(); SB0();
        DSR_B(1, B0, bfB);
        MFMA_Q(0, 0, afX, bfA);
        STG(Abase, ldsA[1], 1, kbc1);
        BARRIER();
        // W2: pre afY=A0h1; mfma q01 t0; stg B0h0'
        LGKM0(); SB0();
        DSR_A(1, A0, afY);
        MFMA_Q(0, 1, afX, bfB);
        if (st) STG(Wbase, ldsB[0], 0, kb0);
        BARRIER();
        // W3: vmcnt(2) [slot1 landed]; pre afX=A1h0; mfma q11 t0; stg A0h0'+B0h1'
        LGKM0(); SB0();
        if (st) VMCNT2(); else VMCNT0();
        DSR_A(0, A1, afX);
        MFMA_Q(1, 1, afY, bfB);
        if (st) { STG(Abase, ldsA[0], 0, kb0); STG(Wbase, ldsB[0], 1, kb0); }
        BARRIER();
        // W4: mfma q10 t0; post bfA=B1n0
        LGKM0(); SB0();
        MFMA_Q(1, 0, afY, bfA);
        DSR_B(0, B1, bfA);
        BARRIER();
        // W5: pre bfB=B1n1; mfma q00 t1; stg A0h1'
        LGKM0(); SB0();
        DSR_B(1, B1, bfB);
        MFMA_Q(0, 0, afX, bfA);
        if (st) STG(Abase, ldsA[0], 1, kb0);
        BARRIER();
        // W6: pre afY=A1h1; mfma q01 t1; stg B1h0'
        LGKM0(); SB0();
        DSR_A(1, A1, afY);
        MFMA_Q(0, 1, afX, bfB);
        if (st) STG(Wbase, ldsB[1], 0, kb1);
        BARRIER();
        // W7: vmcnt(2) [slot0' landed]; pre afX=A0'h0; mfma q11 t1; stg A1h0'+B1h1'
        LGKM0(); SB0();
        if (st) { VMCNT2(); DSR_A(0, A0, afX); }
        MFMA_Q(1, 1, afY, bfB);
        if (st) { STG(Abase, ldsA[1], 0, kb1); STG(Wbase, ldsB[1], 1, kb1); }
        BARRIER();
        // W8: mfma q10 t1; post bfA=B0'n0
        LGKM0(); SB0();
        MFMA_Q(1, 0, afY, bfA);
        if (st) DSR_B(0, B0, bfA);
        BARRIER();
    }

    if (!outf32) {
        unsigned short* O = (unsigned short*)out;
#pragma unroll
        for (int m = 0; m < 8; ++m)
#pragma unroll
            for (int n = 0; n < 4; ++n)
#pragma unroll
                for (int r = 0; r < 4; ++r) {
                    int row = row0 + wm * 128 + m * 16 + kg * 4 + r;
                    int col = col0 + wn * 64 + n * 16 + r16;
                    float bias = (col < HID) ? b0[col]
                               : (col < HID + 512 ? b1[col - HID] : b2[col - HID - 512]);
                    O[(size_t)row * N + col] = f2b(acc[m][n][r] + bias);
                }
    } else {
        float* O = (float*)out;
#pragma unroll
        for (int m = 0; m < 8; ++m)
#pragma unroll
            for (int n = 0; n < 4; ++n)
#pragma unroll
                for (int r = 0; r < 4; ++r) {
                    int row = row0 + wm * 128 + m * 16 + kg * 4 + r;
                    int col = col0 + wn * 64 + n * 16 + r16;
                    O[(size_t)row * N + col] = acc[m][n][r] + b0[col];
                }
    }
#undef DSR_A
#undef DSR_B
#undef MFMA_Q
}

// ---------------- RoPE in-place on q (heads 0..35) and k (36..39) ----------------
__global__ __launch_bounds__(256) void rope_kernel(unsigned short* __restrict__ qkv,
                                                   const float* __restrict__ cos_t,
                                                   const float* __restrict__ sin_t) {
    int idx = blockIdx.x * 256 + threadIdx.x;
    int d = idx & 63;
    int t = idx >> 6;
    int head = t % 40;
    int s = t / 40;
    int base = head < NHEAD ? head * HDIM : HID + (head - NHEAD) * HDIM;
    size_t off = (size_t)s * NQKV + base;
    float x = b2f(qkv[off + d]);
    float y = b2f(qkv[off + d + 64]);
    float c = cos_t[s * HDIM + d];
    float sn = sin_t[s * HDIM + d];
    qkv[off + d]      = f2b(x * c - y * sn);
    qkv[off + d + 64] = f2b(y * c + x * sn);
}

// ---------------- V transpose: qkv V block -> vtg[kvh][128][2048] ----------------
__global__ __launch_bounds__(256) void vtrans_kernel(const unsigned short* __restrict__ qkv,
                                                     unsigned short* __restrict__ vtg) {
    __shared__ unsigned short tile[32][36];
    const int s0 = blockIdx.x * 32, d0 = blockIdx.y * 32, kvh = blockIdx.z;
    const int lid = threadIdx.x;
    {
        int sl = lid >> 3, dc = (lid & 7) * 4;
        u16x4 v = *(const u16x4*)(qkv + (size_t)(s0 + sl) * NQKV + HID + 512 + kvh * HDIM + d0 + dc);
#pragma unroll
        for (int i = 0; i < 4; ++i) tile[sl][dc + i] = v[i];
    }
    __syncthreads();
    {
        int dl = lid >> 3, sc = (lid & 7) * 4;
        u16x4 v;
#pragma unroll
        for (int i = 0; i < 4; ++i) v[i] = tile[sc + i][dl];
        *(u16x4*)(vtg + (size_t)kvh * HDIM * SEQ + (size_t)(d0 + dl) * SEQ + s0 + sc) = v;
    }
}

// ---------------- flash attention, GQA + causal + sliding window ----------------
#define KSTR 136   // Ks row stride (u16): 272B = 68 dw ≡ 4 mod 32 -> 2-way free
#define VSTR 72    // Vt row stride (u16): 144B = 36 dw ≡ 4 mod 32 -> 2-way free
#define PSTR 88
__global__ __launch_bounds__(256) void attn_kernel(const unsigned short* __restrict__ qkv,
                                                   const unsigned short* __restrict__ vtg,
                                                   unsigned short* __restrict__ aout)
{
    __shared__ alignas(16) unsigned short Ks[64 * KSTR];
    __shared__ alignas(16) unsigned short Vt[128 * VSTR];
    __shared__ alignas(16) unsigned short Ps[4 * 16 * PSTR];
    const int h = blockIdx.x, qb = blockIdx.y;
    const int q0 = qb * 64;
    const int kvh = h / 9;
    const int tid = threadIdx.x, wid = tid >> 6, lane = tid & 63;
    const int r16 = lane & 15, kg = lane >> 4;
    const int qbase = q0 + wid * 16;
    const unsigned short* vsrc = vtg + (size_t)kvh * HDIM * SEQ;

    bf16x8 qf[4];
    {
        const unsigned short* qrow = qkv + (size_t)(qbase + r16) * NQKV + h * HDIM;
#pragma unroll
        for (int kk = 0; kk < 4; ++kk)
            qf[kk] = *(const bf16x8*)(qrow + kk * 32 + kg * 8);
    }

    f32x4 o[8] = {};
    float mrow[4], lrow[4];
#pragma unroll
    for (int r = 0; r < 4; ++r) { mrow[r] = -1e30f; lrow[r] = 0.f; }

    int lo = q0 - (WINDOW - 1); if (lo < 0) lo = 0; lo &= ~63;
    unsigned short* myP = Ps + wid * 16 * PSTR;
    const float scale = 0.08838834764831845f;

    u16x8 kreg[4], vreg[4];
#define PREF(KT) \
_Pragma("unroll") for (int j = 0; j < 4; ++j) { \
        int c = tid + j * 256; \
        int key = c >> 4, dc = c & 15; \
        kreg[j] = *(const u16x8*)(qkv + (size_t)((KT) + key) * NQKV + HID + kvh * HDIM + dc * 8); \
        int d = c >> 3, k8 = (c & 7) * 8; \
        vreg[j] = *(const u16x8*)(vsrc + (size_t)d * SEQ + (KT) + k8); \
    }

    PREF(lo);

    for (int kt = lo; kt <= q0; kt += 64) {
#pragma unroll
        for (int j = 0; j < 4; ++j) {
            int c = tid + j * 256;
            int key = c >> 4, dc = c & 15;
            *(u16x8*)(Ks + key * KSTR + dc * 8) = kreg[j];
            int d = c >> 3, k8 = (c & 7) * 8;
            *(u16x8*)(Vt + d * VSTR + k8) = vreg[j];
        }
        __syncthreads();

        if (kt + 64 <= q0) { PREF(kt + 64); }

        f32x4 sc[4] = {};
#pragma unroll
        for (int t = 0; t < 4; ++t)
#pragma unroll
            for (int kk = 0; kk < 4; ++kk) {
                bf16x8 kf = *(const bf16x8*)(Ks + (t * 16 + r16) * KSTR + kk * 32 + kg * 8);
                sc[t] = __builtin_amdgcn_mfma_f32_16x16x32_bf16(qf[kk], kf, sc[t], 0, 0, 0);
            }

        float p[4][4], mt[4];
#pragma unroll
        for (int r = 0; r < 4; ++r) mt[r] = -1e30f;
#pragma unroll
        for (int t = 0; t < 4; ++t)
#pragma unroll
            for (int r = 0; r < 4; ++r) {
                int q = qbase + kg * 4 + r;
                int key = kt + t * 16 + r16;
                bool valid = (key <= q) && (q - key < WINDOW);
                float v = valid ? sc[t][r] * scale : -1e30f;
                p[t][r] = v;
                mt[r] = fmaxf(mt[r], v);
            }
#pragma unroll
        for (int mask = 1; mask <= 8; mask <<= 1)
#pragma unroll
            for (int r = 0; r < 4; ++r)
                mt[r] = fmaxf(mt[r], __shfl_xor(mt[r], mask, 64));

        float alpha[4], tsum[4];
#pragma unroll
        for (int r = 0; r < 4; ++r) {
            float mnew = fmaxf(mrow[r], mt[r]);
            alpha[r] = __expf(mrow[r] - mnew);
            mrow[r] = mnew;
            tsum[r] = 0.f;
        }
#pragma unroll
        for (int t = 0; t < 4; ++t)
#pragma unroll
            for (int r = 0; r < 4; ++r) {
                float e = __expf(p[t][r] - mrow[r]);
                p[t][r] = e;
                tsum[r] += e;
            }
#pragma unroll
        for (int mask = 1; mask <= 8; mask <<= 1)
#pragma unroll
            for (int r = 0; r < 4; ++r)
                tsum[r] += __shfl_xor(tsum[r], mask, 64);
#pragma unroll
        for (int r = 0; r < 4; ++r)
            lrow[r] = lrow[r] * alpha[r] + tsum[r];
#pragma unroll
        for (int n = 0; n < 8; ++n)
#pragma unroll
            for (int r = 0; r < 4; ++r)
                o[n][r] = o[n][r] * alpha[r];

#pragma unroll
        for (int t = 0; t < 4; ++t)
#pragma unroll
            for (int r = 0; r < 4; ++r)
                myP[(kg * 4 + r) * PSTR + t * 16 + r16] = f2b(p[t][r]);
        asm volatile("s_waitcnt lgkmcnt(0)" ::: "memory");

#pragma unroll
        for (int kc = 0; kc < 2; ++kc) {
            bf16x8 pa = *(const bf16x8*)(myP + r16 * PSTR + kc * 32 + kg * 8);
#pragma unroll
            for (int n = 0; n < 8; ++n) {
                bf16x8 vb = *(const bf16x8*)(Vt + (n * 16 + r16) * VSTR + kc * 32 + kg * 8);
                o[n] = __builtin_amdgcn_mfma_f32_16x16x32_bf16(pa, vb, o[n], 0, 0, 0);
            }
        }
        BARRIER();
    }
#undef PREF

#pragma unroll
    for (int n = 0; n < 8; ++n)
#pragma unroll
        for (int r = 0; r < 4; ++r) {
            int q = qbase + kg * 4 + r;
            aout[(size_t)q * HID + h * HDIM + n * 16 + r16] = f2b(o[n][r] / lrow[r]);
        }
}

extern "C" void kernel_launch(void* const* d_in, const int* in_sizes, int n_in,
                              void* d_out, int out_size, void* d_ws, size_t ws_size,
                              hipStream_t stream) {
    const float* hidden = (const float*)d_in[0];
    const float* cos_t = (const float*)d_in[2];
    const float* sin_t = (const float*)d_in[3];
    const float* q_w = (const float*)d_in[4];
    const float* q_b = (const float*)d_in[5];
    const float* k_w = (const float*)d_in[6];
    const float* k_b = (const float*)d_in[7];
    const float* v_w = (const float*)d_in[8];
    const float* v_b = (const float*)d_in[9];
    const float* o_w = (const float*)d_in[10];
    const float* o_b = (const float*)d_in[11];

    char* ws = (char*)d_ws;
    unsigned short* hbf  = (unsigned short*)ws;                   // 2048*4608 bf16
    unsigned short* attn = hbf;                                   // alias: reused after QKV GEMM
    unsigned short* wqkv = (unsigned short*)(ws + 18874368);      // 5632*4608 bf16 (dead after QKV GEMM)
    unsigned short* vtg  = wqkv;                                  // alias: V^T [4][128][2048]
    unsigned short* wo   = (unsigned short*)(ws + 70778880);      // 4608*4608 bf16
    unsigned short* qkv  = (unsigned short*)(ws + 113246208);     // 2048*5632 bf16

    dim3 blk(256);
    conv_all_kernel<<<4096, blk, 0, stream>>>(
        hidden, hbf,                          (SEQ * HID) / 4,
        q_w,    wqkv,                         (HID * HID) / 4,
        k_w,    wqkv + (size_t)HID * HID,     (512 * HID) / 4,
        v_w,    wqkv + (size_t)5120 * HID,    (512 * HID) / 4,
        o_w,    wo,                           (HID * HID) / 4);

    gemm256_kernel<<<dim3(176), dim3(512), 0, stream>>>(hbf, wqkv, qkv, q_b, k_b, v_b, NQKV, HID, 22, 0);
    rope_kernel<<<(SEQ * 40 * 64) / 256, blk, 0, stream>>>(qkv, cos_t, sin_t);
    vtrans_kernel<<<dim3(SEQ / 32, HDIM / 32, NKVH), blk, 0, stream>>>(qkv, vtg);
    attn_kernel<<<dim3(NHEAD, SEQ / 64), blk, 0, stream>>>(qkv, vtg, attn);
    gemm256_kernel<<<dim3(144), dim3(512), 0, stream>>>(attn, wo, d_out, o_b, nullptr, nullptr, HID, HID, 18, 1);
}